// Round 12
// baseline (1306.415 us; speedup 1.0000x reference)
//
#include <hip/hip_runtime.h>
#include <hip/hip_bf16.h>

typedef __hip_bfloat16 hbf16;
typedef __bf16 bf16x8 __attribute__((ext_vector_type(8)));
typedef float floatx4 __attribute__((ext_vector_type(4)));

#define N_ATOMS 4096
#define N_BONDS 8192
#define FDIM 133
#define BFDIM 147
#define HID 256
#define APM 64
#define NMOL 64
#define FA_S 160
#define FB_S 160
#define AI_S 416
#define CS 4       // flash column splits

struct P8 { float* p[4]; };
struct PROJ { const float* A[4]; const hbf16* w[4]; void* outp[4]; int mode[4]; };
struct CvtTab { const void* src[6]; float* dst[6]; int n[6]; };
struct WTab { const void* src[11]; hbf16* dst[11]; int K[11]; int Hout[11]; int Kp[11]; int total[11]; };

__device__ __forceinline__ float bcvt(hbf16 x) { return __bfloat162float(x); }

__device__ __forceinline__ float load_in(const void* src, int i, int f32flag)
{
    return f32flag ? ((const float*)src)[i] : bcvt(((const hbf16*)src)[i]);
}

__device__ __forceinline__ void split8(const float4 a0, const float4 a1,
                                       bf16x8& hi, bf16x8& lo)
{
    const float v[8] = {a0.x, a0.y, a0.z, a0.w, a1.x, a1.y, a1.z, a1.w};
    #pragma unroll
    for (int i = 0; i < 8; i++) {
        const __bf16 h = (__bf16)v[i];
        hi[i] = h;
        lo[i] = (__bf16)(v[i] - (float)h);
    }
}

// ---------------- dtype detect ----------------
__global__ void detect_kernel(const unsigned short* __restrict__ probe, int* __restrict__ flag)
{
    const int t = threadIdx.x;
    float mx = 0.f;
    for (int i = t; i < 4096; i += 64) {
        unsigned int u = ((unsigned int)probe[i]) << 16;
        float v;
        __builtin_memcpy(&v, &u, 4);
        v = fabsf(v);
        if (!(v == v)) v = 0.f;
        if (v > 1e6f) v = 1e6f;
        mx = fmaxf(mx, v);
    }
    #pragma unroll
    for (int o = 32; o > 0; o >>= 1) mx = fmaxf(mx, __shfl_xor(mx, o));
    if (t == 0) *flag = (mx > 100.f) ? 1 : 0;   // 1 = f32 data, 0 = bf16 data
}

__global__ void small_cvt_kernel(CvtTab tab, const int* __restrict__ flag)
{
    const int f32 = *flag;
    for (int s = 0; s < 6; s++)
        for (int i = threadIdx.x; i < tab.n[s]; i += 256)
            tab.dst[s][i] = load_in(tab.src[s], i, f32);
}

__global__ void cvt_pad_kernel(const void* __restrict__ src, float* __restrict__ dst,
                               int N, int K, int Kp, const int* __restrict__ flag)
{
    const int i = blockIdx.x * 256 + threadIdx.x;
    if (i >= N * Kp) return;
    const int r = i / Kp, k = i - r * Kp;
    dst[i] = (k < K) ? load_in(src, r * K + k, *flag) : 0.f;
}

__global__ void wt_all_kernel(WTab tab, const int* __restrict__ flag)
{
    const int wid = blockIdx.y;
    const int f32 = *flag;
    const int tot = tab.total[wid], Kp = tab.Kp[wid], K = tab.K[wid], Hout = tab.Hout[wid];
    hbf16* dst = tab.dst[wid];
    const void* src = tab.src[wid];
    for (int i = blockIdx.x * 256 + threadIdx.x; i < tot; i += gridDim.x * 256) {
        const int n = i / Kp, k = i - n * Kp;
        const float v = (k < K && n < Hout) ? load_in(src, k * Hout + n, f32) : 0.f;
        dst[i] = __float2bfloat16(v);
    }
}

// ---------------- bf16 MFMA GEMM, LDS-free, multi-emit ----------------
__global__ __launch_bounds__(256)
void mgemm_kernel(const float* __restrict__ A, int lda, const hbf16* __restrict__ Wt,
                  const float* __restrict__ bias,
                  float* __restrict__ Cf, float* __restrict__ Cf2, int ldcf,
                  hbf16* __restrict__ Cbh, hbf16* __restrict__ Cbl, int ldcb,
                  hbf16* __restrict__ CbT, int ldct,
                  int Hout, int HoutStore, int relu)
{
    const int t = threadIdx.x, w = t >> 6, ln = t & 63;
    const int lane16 = ln & 15, quad = ln >> 4;
    const int rb = blockIdx.y * 64 + w * 16, cb = blockIdx.x * 64;
    const floatx4 zero4 = {0.f, 0.f, 0.f, 0.f};
    floatx4 acc[4] = {zero4, zero4, zero4, zero4};
    const float* ar = A + (size_t)(rb + lane16) * lda + quad * 8;
    for (int kk = 0; kk < lda; kk += 32) {
        const float4 a0 = *(const float4*)(ar + kk);
        const float4 a1 = *(const float4*)(ar + kk + 4);
        bf16x8 af;
        af[0] = (__bf16)a0.x; af[1] = (__bf16)a0.y; af[2] = (__bf16)a0.z; af[3] = (__bf16)a0.w;
        af[4] = (__bf16)a1.x; af[5] = (__bf16)a1.y; af[6] = (__bf16)a1.z; af[7] = (__bf16)a1.w;
        #pragma unroll
        for (int nt = 0; nt < 4; nt++) {
            const bf16x8 bf =
                *(const bf16x8*)&Wt[(size_t)(cb + nt * 16 + lane16) * lda + kk + quad * 8];
            acc[nt] = __builtin_amdgcn_mfma_f32_16x16x32_bf16(af, bf, acc[nt], 0, 0, 0);
        }
    }
    #pragma unroll
    for (int nt = 0; nt < 4; nt++) {
        const int n = cb + nt * 16 + lane16;
        if (n >= HoutStore) continue;
        const bool valid = n < Hout;
        const float bv = (bias && valid) ? bias[n] : 0.f;
        #pragma unroll
        for (int r = 0; r < 4; r++) {
            const int m = rb + quad * 4 + r;
            float v = valid ? acc[nt][r] + bv : 0.f;
            if (relu) v = fmaxf(v, 0.f);
            if (Cf)  Cf[(size_t)m * ldcf + n] = v;
            if (Cf2) Cf2[(size_t)m * ldcf + n] = fmaxf(v, 0.f);
            if (Cbh) {
                const hbf16 h = __float2bfloat16(v);
                Cbh[(size_t)m * ldcb + n] = h;
                if (Cbl) Cbl[(size_t)m * ldcb + n] = __float2bfloat16(v - bcvt(h));
            }
            if (CbT) CbT[(size_t)n * ldct + m] = __float2bfloat16(v);
        }
    }
}

// ---------------- fused projections: z selects {dmpnn(f32), Q(bf16), K(bf16), V^T(bf16)} -----
__global__ __launch_bounds__(256)
void proj_kernel(PROJ p)
{
    const int z = blockIdx.z;
    const float* __restrict__ A = p.A[z];
    const hbf16* __restrict__ Wt = p.w[z];
    void* __restrict__ outp = p.outp[z];
    const int mode = p.mode[z];
    const int t = threadIdx.x, w = t >> 6, ln = t & 63;
    const int lane16 = ln & 15, quad = ln >> 4;
    const int rb = blockIdx.y * 64 + w * 16, cb = blockIdx.x * 64;
    const floatx4 zero4 = {0.f, 0.f, 0.f, 0.f};
    floatx4 acc[4] = {zero4, zero4, zero4, zero4};
    const float* ar = A + (size_t)(rb + lane16) * HID + quad * 8;
    for (int kk = 0; kk < HID; kk += 32) {
        const float4 a0 = *(const float4*)(ar + kk);
        const float4 a1 = *(const float4*)(ar + kk + 4);
        bf16x8 af;
        af[0] = (__bf16)a0.x; af[1] = (__bf16)a0.y; af[2] = (__bf16)a0.z; af[3] = (__bf16)a0.w;
        af[4] = (__bf16)a1.x; af[5] = (__bf16)a1.y; af[6] = (__bf16)a1.z; af[7] = (__bf16)a1.w;
        #pragma unroll
        for (int nt = 0; nt < 4; nt++) {
            const bf16x8 bf =
                *(const bf16x8*)&Wt[(size_t)(cb + nt * 16 + lane16) * HID + kk + quad * 8];
            acc[nt] = __builtin_amdgcn_mfma_f32_16x16x32_bf16(af, bf, acc[nt], 0, 0, 0);
        }
    }
    #pragma unroll
    for (int nt = 0; nt < 4; nt++) {
        const int n = cb + nt * 16 + lane16;
        #pragma unroll
        for (int r = 0; r < 4; r++) {
            const int m = rb + quad * 4 + r;
            const float v = acc[nt][r];
            if (mode == 2)      ((float*)outp)[(size_t)m * HID + n] = v;
            else if (mode == 0) ((hbf16*)outp)[(size_t)m * HID + n] = __float2bfloat16(v);
            else                ((hbf16*)outp)[(size_t)n * N_BONDS + m] = __float2bfloat16(v);
        }
    }
}

// ---------------- fused per-molecule atom attention + LayerNorm ----------------
__global__ __launch_bounds__(256)
void atom_fused_kernel(const float* __restrict__ qa, const float* __restrict__ ka,
                       const hbf16* __restrict__ vT, const float* __restrict__ f_atoms_p,
                       const float* __restrict__ ln_g, const float* __restrict__ ln_b,
                       float* __restrict__ f_e)
{
    __shared__ float S[64][68];
    __shared__ __bf16 P[64][72];
    __shared__ float Y[64][136];
    const int m = blockIdx.x, t = threadIdx.x;
    const int w = t >> 6, ln = t & 63;
    const int lane16 = ln & 15, quad = ln >> 4;
    const int base = m * APM;
    const floatx4 zero4 = {0.f, 0.f, 0.f, 0.f};

    {
        floatx4 acc[4] = {zero4, zero4, zero4, zero4};
        const float* arow = qa + (size_t)(base + w * 16 + lane16) * FA_S + quad * 8;
        #pragma unroll
        for (int ks = 0; ks < 5; ks++) {
            bf16x8 ah, al;
            split8(*(const float4*)(arow + ks * 32), *(const float4*)(arow + ks * 32 + 4), ah, al);
            #pragma unroll
            for (int nt = 0; nt < 4; nt++) {
                const float* brow = ka + (size_t)(base + nt * 16 + lane16) * FA_S + ks * 32 + quad * 8;
                bf16x8 bh, bl;
                split8(*(const float4*)brow, *(const float4*)(brow + 4), bh, bl);
                acc[nt] = __builtin_amdgcn_mfma_f32_16x16x32_bf16(ah, bh, acc[nt], 0, 0, 0);
                acc[nt] = __builtin_amdgcn_mfma_f32_16x16x32_bf16(al, bh, acc[nt], 0, 0, 0);
                acc[nt] = __builtin_amdgcn_mfma_f32_16x16x32_bf16(ah, bl, acc[nt], 0, 0, 0);
            }
        }
        const float scale = 1.f / sqrtf(133.f);
        #pragma unroll
        for (int nt = 0; nt < 4; nt++)
            #pragma unroll
            for (int r = 0; r < 4; r++)
                S[w * 16 + quad * 4 + r][nt * 16 + lane16] = acc[nt][r] * scale;
    }
    for (int r = w * 16; r < w * 16 + 16; r++) {
        const float x = S[r][ln];
        float mx = x;
        #pragma unroll
        for (int o = 32; o > 0; o >>= 1) mx = fmaxf(mx, __shfl_xor(mx, o));
        const float p = __expf(x - mx);
        float sm = p;
        #pragma unroll
        for (int o = 32; o > 0; o >>= 1) sm += __shfl_xor(sm, o);
        P[r][ln] = (__bf16)(p / sm);
    }
    {
        floatx4 o[9];
        #pragma unroll
        for (int i = 0; i < 9; i++) o[i] = zero4;
        #pragma unroll
        for (int ks = 0; ks < 2; ks++) {
            const bf16x8 af = *(const bf16x8*)&P[w * 16 + lane16][ks * 32 + quad * 8];
            #pragma unroll
            for (int nt = 0; nt < 9; nt++) {
                const bf16x8 bfv =
                    *(const bf16x8*)&vT[(size_t)(nt * 16 + lane16) * N_ATOMS + base + ks * 32 + quad * 8];
                o[nt] = __builtin_amdgcn_mfma_f32_16x16x32_bf16(af, bfv, o[nt], 0, 0, 0);
            }
        }
        #pragma unroll
        for (int nt = 0; nt < 9; nt++) {
            const int f = nt * 16 + lane16;
            if (f >= FDIM) continue;
            #pragma unroll
            for (int r = 0; r < 4; r++) {
                const int a = w * 16 + quad * 4 + r;
                Y[a][f] = f_atoms_p[(size_t)(base + a) * FA_S + f] + o[nt][r];
            }
        }
    }
    for (int r = w * 16; r < w * 16 + 16; r++) {
        float sum = 0.f, sq = 0.f;
        for (int f = ln; f < FDIM; f += 64) { const float v = Y[r][f]; sum += v; sq += v * v; }
        #pragma unroll
        for (int o = 32; o > 0; o >>= 1) { sum += __shfl_xor(sum, o); sq += __shfl_xor(sq, o); }
        const float mu = sum / FDIM;
        const float var = sq / FDIM - mu * mu;
        const float rstd = rsqrtf(var + 1e-5f);
        for (int f = ln; f < FDIM; f += 64) {
            const float v = (Y[r][f] - mu) * rstd;
            f_e[(size_t)(base + r) * FDIM + f] = v * ln_g[f] + ln_b[f];
        }
    }
}

// ---------------- fused per-molecule pooling ----------------
__global__ __launch_bounds__(256)
void pool_fused_kernel(const float* __restrict__ hmWa, const float* __restrict__ atom_h,
                       const hbf16* __restrict__ hm_hi, const hbf16* __restrict__ hm_lo,
                       const hbf16* __restrict__ hmT, const hbf16* __restrict__ Wtb,
                       const float* __restrict__ Wb_b, void* __restrict__ out,
                       const int* __restrict__ flag)
{
    __shared__ float S[64][68];
    __shared__ __bf16 P[64][72];
    __shared__ __bf16 att[64][264];
    const int m = blockIdx.x, t = threadIdx.x;
    const int w = t >> 6, ln = t & 63;
    const int lane16 = ln & 15, quad = ln >> 4;
    const int base = m * APM;
    const floatx4 zero4 = {0.f, 0.f, 0.f, 0.f};

    {
        floatx4 acc[4] = {zero4, zero4, zero4, zero4};
        const float* arow = hmWa + (size_t)(base + w * 16 + lane16) * HID + quad * 8;
        #pragma unroll
        for (int ks = 0; ks < 8; ks++) {
            bf16x8 ah, al;
            split8(*(const float4*)(arow + ks * 32), *(const float4*)(arow + ks * 32 + 4), ah, al);
            #pragma unroll
            for (int nt = 0; nt < 4; nt++) {
                const size_t bidx = (size_t)(base + nt * 16 + lane16) * HID + ks * 32 + quad * 8;
                const bf16x8 bh = *(const bf16x8*)&hm_hi[bidx];
                const bf16x8 bl = *(const bf16x8*)&hm_lo[bidx];
                acc[nt] = __builtin_amdgcn_mfma_f32_16x16x32_bf16(ah, bh, acc[nt], 0, 0, 0);
                acc[nt] = __builtin_amdgcn_mfma_f32_16x16x32_bf16(al, bh, acc[nt], 0, 0, 0);
                acc[nt] = __builtin_amdgcn_mfma_f32_16x16x32_bf16(ah, bl, acc[nt], 0, 0, 0);
            }
        }
        #pragma unroll
        for (int nt = 0; nt < 4; nt++)
            #pragma unroll
            for (int r = 0; r < 4; r++)
                S[w * 16 + quad * 4 + r][nt * 16 + lane16] = acc[nt][r];
    }
    for (int r = w * 16; r < w * 16 + 16; r++) {
        const float x = S[r][ln];
        float mx = x;
        #pragma unroll
        for (int o = 32; o > 0; o >>= 1) mx = fmaxf(mx, __shfl_xor(mx, o));
        const float p = __expf(x - mx);
        float sm = p;
        #pragma unroll
        for (int o = 32; o > 0; o >>= 1) sm += __shfl_xor(sm, o);
        P[r][ln] = (__bf16)(p / sm);
    }
    __syncthreads();
    {
        floatx4 o3[4][4];
        #pragma unroll
        for (int mt = 0; mt < 4; mt++)
            #pragma unroll
            for (int nt = 0; nt < 4; nt++) o3[mt][nt] = zero4;
        #pragma unroll
        for (int ks = 0; ks < 2; ks++) {
            bf16x8 af[4];
            #pragma unroll
            for (int mt = 0; mt < 4; mt++)
                af[mt] = *(const bf16x8*)&P[mt * 16 + lane16][ks * 32 + quad * 8];
            #pragma unroll
            for (int nt = 0; nt < 4; nt++) {
                const bf16x8 bfv = *(const bf16x8*)
                    &hmT[(size_t)(w * 64 + nt * 16 + lane16) * N_ATOMS + base + ks * 32 + quad * 8];
                #pragma unroll
                for (int mt = 0; mt < 4; mt++)
                    o3[mt][nt] = __builtin_amdgcn_mfma_f32_16x16x32_bf16(af[mt], bfv, o3[mt][nt], 0, 0, 0);
            }
        }
        #pragma unroll
        for (int mt = 0; mt < 4; mt++)
            #pragma unroll
            for (int nt = 0; nt < 4; nt++)
                #pragma unroll
                for (int r = 0; r < 4; r++)
                    att[mt * 16 + quad * 4 + r][w * 64 + nt * 16 + lane16] = (__bf16)o3[mt][nt][r];
    }
    __syncthreads();
    {
        floatx4 o5[4][4];
        #pragma unroll
        for (int mt = 0; mt < 4; mt++)
            #pragma unroll
            for (int nt = 0; nt < 4; nt++) o5[mt][nt] = zero4;
        #pragma unroll
        for (int ks = 0; ks < 8; ks++) {
            bf16x8 af[4];
            #pragma unroll
            for (int mt = 0; mt < 4; mt++)
                af[mt] = *(const bf16x8*)&att[mt * 16 + lane16][ks * 32 + quad * 8];
            #pragma unroll
            for (int nt = 0; nt < 4; nt++) {
                const bf16x8 bfv = *(const bf16x8*)
                    &Wtb[(size_t)(w * 64 + nt * 16 + lane16) * HID + ks * 32 + quad * 8];
                #pragma unroll
                for (int mt = 0; mt < 4; mt++)
                    o5[mt][nt] = __builtin_amdgcn_mfma_f32_16x16x32_bf16(af[mt], bfv, o5[mt][nt], 0, 0, 0);
            }
        }
        #pragma unroll
        for (int nt = 0; nt < 4; nt++) {
            const int n = w * 64 + nt * 16 + lane16;
            const float bv = Wb_b[n];
            float s = 0.f;
            #pragma unroll
            for (int mt = 0; mt < 4; mt++)
                #pragma unroll
                for (int r = 0; r < 4; r++)
                    s += fmaxf(o5[mt][nt][r] + bv, 0.f);
            s += __shfl_xor(s, 16);
            s += __shfl_xor(s, 32);
            if (quad == 0) {
                float hsum = 0.f;
                for (int a = 0; a < APM; a++)
                    hsum += atom_h[(size_t)(base + a) * HID + n];
                const float v = (s + hsum) * (1.f / 64.f);
                if (*flag) ((float*)out)[m * HID + n] = v;
                else       ((hbf16*)out)[m * HID + n] = __float2bfloat16(v);
            }
        }
    }
}

// ---------------- flash attention v7: col-half split for the 128-reg occupancy bucket -------
// HW occupancy buckets (m69): waves/SIMD = 8/4/2 at total regs <=64/128/256 (VGPR+AGPR,
// VGPR_Count excludes AGPR). R6-locked config = 92+64 = 156 -> <=256 bucket -> 2 waves/SIMD;
// R9's waves_per_eu(3,3) could NEVER give 3 (148 regs is still the 256 bucket) - it spilled
// for nothing. Only reachable improvement: <=128 bucket -> 4 waves/SIMD.
// Design: 4 waves = 2 row-groups x 2 col-halves. Each wave: full S+softmax for its 16 rows
// (QK duplicated across col-halves, +50% MFMA ops - cheap at 16% util), PV over 8 n-tiles
// -> O = 32 AGPR. Ledger: ~92 VGPR + 32 AGPR = 124 <= 128. launch_bounds(256,4) pins it
// (forcing 128 for ~124 live, unlike R5 which forced 64 for ~192). CS=4, 32-row blocks,
// grid 1024 = 4 blocks/CU. Failure signature: WRITE >> 34MB => spilled, revert.
__global__ __launch_bounds__(256, 4)
void flash_kernel(const hbf16* __restrict__ Qg, const hbf16* __restrict__ Kg,
                  const hbf16* __restrict__ Vtg, P8 parts, float2* __restrict__ ml)
{
    __shared__ __align__(16) __bf16 Ks[32][256];   // XOR-swizzled: chunk c -> c ^ (row & 31)
    __shared__ __align__(16) __bf16 Vt[256][32];   // XOR-swizzled: chunk c -> c ^ (row & 3)
    __shared__ __align__(16) __bf16 Ps[4][16][40]; // per-wave P copy (col-halves duplicate)

    const int t = threadIdx.x, w = t >> 6, ln = t & 63;
    const int lane16 = ln & 15, quad = ln >> 4;
    const int rg = w & 1, ch = w >> 1;
    const int cs = blockIdx.x;
    const int rw = blockIdx.y * 32 + rg * 16;
    float* __restrict__ part = parts.p[cs];

    bf16x8 qf[8];
    #pragma unroll
    for (int ks = 0; ks < 8; ks++)
        qf[ks] = *(const bf16x8*)&Qg[(size_t)(rw + lane16) * HID + ks * 32 + quad * 8];

    const floatx4 zero4 = {0.f, 0.f, 0.f, 0.f};
    floatx4 O[8];
    #pragma unroll
    for (int i = 0; i < 8; i++) O[i] = zero4;
    float mrow[4] = {-1e30f, -1e30f, -1e30f, -1e30f};
    float lrow[4] = {0.f, 0.f, 0.f, 0.f};
    const float scale = 0.0625f;  // 1/sqrt(256)

    const int cbeg = cs * (N_BONDS / CS), cend = cbeg + N_BONDS / CS;
    for (int c0 = cbeg; c0 < cend; c0 += 32) {
        __syncthreads();
        #pragma unroll
        for (int ii = 0; ii < 4; ii++) {              // K tile 32x256 (swizzled)
            const int idx = t + ii * 256;
            const int row = idx >> 5, c = idx & 31;
            *(bf16x8*)&Ks[row][(c ^ (row & 31)) * 8] =
                *(const bf16x8*)&Kg[(size_t)(c0 + row) * HID + c * 8];
        }
        #pragma unroll
        for (int ii = 0; ii < 4; ii++) {              // V^T tile 256x32 (swizzled)
            const int idx = t + ii * 256;
            const int row = idx >> 2, c = idx & 3;
            *(bf16x8*)&Vt[row][(c ^ (row & 3)) * 8] =
                *(const bf16x8*)&Vtg[(size_t)row * N_BONDS + c0 + c * 8];
        }
        __syncthreads();

        floatx4 s0 = zero4, s1 = zero4;
        #pragma unroll
        for (int ks = 0; ks < 8; ks++) {
            const int chk = ks * 4 + quad;
            const bf16x8 b0 = *(bf16x8*)&Ks[lane16][(chk ^ lane16) * 8];
            const bf16x8 b1 = *(bf16x8*)&Ks[16 + lane16][(chk ^ (16 + lane16)) * 8];
            s0 = __builtin_amdgcn_mfma_f32_16x16x32_bf16(qf[ks], b0, s0, 0, 0, 0);
            s1 = __builtin_amdgcn_mfma_f32_16x16x32_bf16(qf[ks], b1, s1, 0, 0, 0);
        }
        float alpha[4];
        #pragma unroll
        for (int r = 0; r < 4; r++) {
            const float v0 = s0[r] * scale, v1 = s1[r] * scale;
            float mx = fmaxf(v0, v1);
            #pragma unroll
            for (int o = 8; o > 0; o >>= 1) mx = fmaxf(mx, __shfl_xor(mx, o));
            const float mnew = fmaxf(mrow[r], mx);
            const float p0 = __expf(v0 - mnew), p1 = __expf(v1 - mnew);
            float ps = p0 + p1;
            #pragma unroll
            for (int o = 8; o > 0; o >>= 1) ps += __shfl_xor(ps, o);
            alpha[r] = __expf(mrow[r] - mnew);
            lrow[r] = lrow[r] * alpha[r] + ps;
            mrow[r] = mnew;
            const int row = quad * 4 + r;
            Ps[w][row][lane16] = (__bf16)p0;
            Ps[w][row][16 + lane16] = (__bf16)p1;
        }
        const bool need = (alpha[0] < 1.f) | (alpha[1] < 1.f) | (alpha[2] < 1.f) | (alpha[3] < 1.f);
        if (__any(need)) {
            #pragma unroll
            for (int nt = 0; nt < 8; nt++)
                #pragma unroll
                for (int r = 0; r < 4; r++) O[nt][r] *= alpha[r];
        }
        const bf16x8 pf = *(bf16x8*)&Ps[w][lane16][quad * 8];
        #pragma unroll
        for (int nt = 0; nt < 8; nt++) {
            const int vrow = ch * 128 + nt * 16 + lane16;
            const bf16x8 vf = *(bf16x8*)&Vt[vrow][(quad ^ (vrow & 3)) * 8];
            O[nt] = __builtin_amdgcn_mfma_f32_16x16x32_bf16(pf, vf, O[nt], 0, 0, 0);
        }
    }
    #pragma unroll
    for (int r = 0; r < 4; r++) {
        const int row = rw + quad * 4 + r;
        #pragma unroll
        for (int nt = 0; nt < 8; nt++)
            part[(size_t)row * HID + ch * 128 + nt * 16 + lane16] = O[nt][r];
        if (ch == 0 && lane16 == 0) ml[cs * N_BONDS + row] = make_float2(mrow[r], lrow[r]);
    }
}

// ---------------- fused: combine partials -> @Wa -> sigmoid-gate -> msg ----------------
__global__ __launch_bounds__(256)
void attcombine_kernel(P8 parts, const float2* __restrict__ ml, const hbf16* __restrict__ Wta,
                       const float* __restrict__ inputs, const float* __restrict__ dmpnn,
                       const float* __restrict__ ww, const float* __restrict__ wb,
                       float* __restrict__ msg)
{
    __shared__ __align__(16) __bf16 Av[32][264];
    __shared__ float wgtS[32][6];     // 4 weights + inv-denominator
    __shared__ float dotS[32][2];
    const int t = threadIdx.x, w = t >> 6, ln = t & 63;
    const int lane16 = ln & 15, quad = ln >> 4;
    const int rb = blockIdx.x * 32;
    const int mt = w & 1, nh = w >> 1;

    if (t < 32) {
        const int row = rb + t;
        float2 e[CS];
        float M = -1e30f;
        #pragma unroll
        for (int i = 0; i < CS; i++) { e[i] = ml[i * N_BONDS + row]; M = fmaxf(M, e[i].x); }
        float den = 0.f;
        #pragma unroll
        for (int i = 0; i < CS; i++) {
            const float g = __expf(e[i].x - M);
            wgtS[t][i] = g;
            den += g * e[i].y;
        }
        wgtS[t][CS] = 1.f / den;
    }
    __syncthreads();
    for (int e = t; e < 32 * 64; e += 256) {
        const int row = e >> 6, c4 = (e & 63) * 4;
        const float inv = wgtS[row][CS];
        float ax = 0.f, ay = 0.f, az = 0.f, aw = 0.f;
        #pragma unroll
        for (int i = 0; i < CS; i++) {
            const float g = wgtS[row][i];
            const float4 pv = *(const float4*)&parts.p[i][(size_t)(rb + row) * HID + c4];
            ax += g * pv.x; ay += g * pv.y; az += g * pv.z; aw += g * pv.w;
        }
        Av[row][c4 + 0] = (__bf16)(ax * inv);
        Av[row][c4 + 1] = (__bf16)(ay * inv);
        Av[row][c4 + 2] = (__bf16)(az * inv);
        Av[row][c4 + 3] = (__bf16)(aw * inv);
    }
    __syncthreads();

    const floatx4 zero4 = {0.f, 0.f, 0.f, 0.f};
    floatx4 acc[8];
    #pragma unroll
    for (int nt = 0; nt < 8; nt++) acc[nt] = zero4;
    #pragma unroll
    for (int ks = 0; ks < 8; ks++) {
        const bf16x8 af = *(const bf16x8*)&Av[mt * 16 + lane16][ks * 32 + quad * 8];
        #pragma unroll
        for (int nt = 0; nt < 8; nt++) {
            const bf16x8 bf = *(const bf16x8*)
                &Wta[(size_t)(nh * 128 + nt * 16 + lane16) * HID + ks * 32 + quad * 8];
            acc[nt] = __builtin_amdgcn_mfma_f32_16x16x32_bf16(af, bf, acc[nt], 0, 0, 0);
        }
    }
    float w2[8];
    #pragma unroll
    for (int nt = 0; nt < 8; nt++) w2[nt] = ww[HID + nh * 128 + nt * 16 + lane16];
    #pragma unroll
    for (int r = 0; r < 4; r++) {
        const int row = rb + mt * 16 + quad * 4 + r;
        float dot = 0.f;
        #pragma unroll
        for (int nt = 0; nt < 8; nt++) {
            const int col = nh * 128 + nt * 16 + lane16;
            dot += acc[nt][r] * w2[nt] + dmpnn[(size_t)row * HID + col] * ww[col];
        }
        #pragma unroll
        for (int o = 8; o > 0; o >>= 1) dot += __shfl_xor(dot, o);
        if (lane16 == 0) dotS[row - rb][nh] = dot;
    }
    __syncthreads();
    #pragma unroll
    for (int r = 0; r < 4; r++) {
        const int row = rb + mt * 16 + quad * 4 + r;
        const float alpha = 1.f / (1.f + __expf(-(dotS[row - rb][0] + dotS[row - rb][1] + wb[0])));
        #pragma unroll
        for (int nt = 0; nt < 8; nt++) {
            const int col = nh * 128 + nt * 16 + lane16;
            const float dv = dmpnn[(size_t)row * HID + col];
            const float v = inputs[(size_t)row * HID + col] + alpha * dv + (1.f - alpha) * acc[nt][r];
            msg[(size_t)row * HID + col] = fmaxf(v, 0.f);
        }
    }
}

// ---------------- small fused kernels ----------------
__global__ void gather_kernel(const float* __restrict__ msg, const int* __restrict__ a2b,
                              float* __restrict__ amsg)
{
    const int a = blockIdx.x, h = threadIdx.x;
    float s = 0.f;
    #pragma unroll
    for (int i = 0; i < 6; i++) {
        const int b = a2b[a * 6 + i];
        s += msg[(size_t)b * HID + h];
    }
    amsg[(size_t)a * HID + h] = s;
}

__global__ void gather_pre_kernel(const float* __restrict__ msg, const int* __restrict__ a2b,
                                  const int* __restrict__ b2a, const int* __restrict__ b2revb,
                                  float* __restrict__ pre)
{
    const int b = blockIdx.x, h = threadIdx.x;
    const int a = b2a[b];
    float s = -msg[(size_t)b2revb[b] * HID + h];
    #pragma unroll
    for (int i = 0; i < 6; i++)
        s += msg[(size_t)a2b[a * 6 + i] * HID + h];
    pre[(size_t)b * HID + h] = s;
}

__global__ void concat_kernel(const float* __restrict__ fe, const float* __restrict__ amsg,
                              float* __restrict__ ai)
{
    const int a = blockIdx.x, t = threadIdx.x;
    for (int f = t; f < FDIM; f += 256) ai[(size_t)a * AI_S + f] = fe[(size_t)a * FDIM + f];
    for (int h = t; h < HID; h += 256) ai[(size_t)a * AI_S + FDIM + h] = amsg[(size_t)a * HID + h];
    for (int z = t; z < AI_S - FDIM - HID; z += 256) ai[(size_t)a * AI_S + FDIM + HID + z] = 0.f;
}

// ---------------- launch ----------------
extern "C" void kernel_launch(void* const* d_in, const int* in_sizes, int n_in,
                              void* d_out, int out_size, void* d_ws, size_t ws_size,
                              hipStream_t stream)
{
    const int* a2b    = (const int*)d_in[19];
    const int* b2a    = (const int*)d_in[20];
    const int* b2revb = (const int*)d_in[21];

    float* ws = (float*)d_ws;
    size_t off = 0;
    auto alloc = [&](size_t n) { float* p = ws + off; off += (n + 63) & ~(size_t)63; return p; };
    int* flag = (int*)alloc(64);

    float* ln_g     = alloc(FDIM);
    float* ln_b     = alloc(FDIM);
    float* Walpha_w = alloc(2 * HID);
    float* Walpha_b = alloc(64);
    float* Wo_b     = alloc(HID);
    float* Wb_b     = alloc(HID);
    float* f_atoms_p = alloc((size_t)N_ATOMS * FA_S);
    float* f_bonds_p = alloc((size_t)N_BONDS * FB_S);
    auto balloc = [&](size_t n) { return (hbf16*)alloc((n + 1) / 2); };
    hbf16* Wt_qa = balloc((size_t)192 * FA_S);
    hbf16* Wt_ka = balloc((size_t)192 * FA_S);
    hbf16* Wt_va = balloc((size_t)192 * FA_S);
    hbf16* Wt_i  = balloc((size_t)HID * FB_S);
    hbf16* Wt_h  = balloc((size_t)HID * HID);
    hbf16* Wt_q  = balloc((size_t)HID * HID);
    hbf16* Wt_k  = balloc((size_t)HID * HID);
    hbf16* Wt_v  = balloc((size_t)HID * HID);
    hbf16* Wt_a  = balloc((size_t)HID * HID);
    hbf16* Wt_b  = balloc((size_t)HID * HID);
    hbf16* Wt_o  = balloc((size_t)HID * AI_S);

    float* f_e    = alloc((size_t)N_ATOMS * FDIM);
    float* inputs = alloc((size_t)N_BONDS * HID);
    float* msg    = alloc((size_t)N_BONDS * HID);
    float* buf1   = alloc((size_t)N_BONDS * HID);   // qa | pre | part0 | a_input
    float* buf2   = alloc((size_t)N_BONDS * HID);   // ka | dmpnn
    float* buf3   = alloc((size_t)N_BONDS * HID);   // vT | part1 | hmWa
    float* buf4   = alloc((size_t)N_BONDS * HID);   // part2 | atom_h
    float* pnew   = alloc((size_t)N_BONDS * HID);   // part3
    float* amsg   = alloc((size_t)N_ATOMS * HID);
    float2* ml    = (float2*)alloc((size_t)CS * N_BONDS * 2);
    hbf16* Qb  = balloc((size_t)N_BONDS * HID);     // later: hm_hi
    hbf16* Kb  = balloc((size_t)N_BONDS * HID);     // later: hm_lo
    hbf16* Vtg = balloc((size_t)N_BONDS * HID);     // later: hmT
    hbf16* vTa = (hbf16*)buf3;                       // atom V^T [192][4096]

    detect_kernel<<<1, 64, 0, stream>>>((const unsigned short*)d_in[1], flag);

    CvtTab ct;
    ct.src[0] = d_in[5];  ct.dst[0] = ln_g;     ct.n[0] = FDIM;
    ct.src[1] = d_in[6];  ct.dst[1] = ln_b;     ct.n[1] = FDIM;
    ct.src[2] = d_in[13]; ct.dst[2] = Walpha_w; ct.n[2] = 2 * HID;
    ct.src[3] = d_in[14]; ct.dst[3] = Walpha_b; ct.n[3] = 1;
    ct.src[4] = d_in[16]; ct.dst[4] = Wo_b;     ct.n[4] = HID;
    ct.src[5] = d_in[18]; ct.dst[5] = Wb_b;     ct.n[5] = HID;
    small_cvt_kernel<<<1, 256, 0, stream>>>(ct, flag);

    cvt_pad_kernel<<<(N_ATOMS * FA_S + 255) / 256, 256, 0, stream>>>(
        d_in[0], f_atoms_p, N_ATOMS, FDIM, FA_S, flag);
    cvt_pad_kernel<<<(N_BONDS * FB_S + 255) / 256, 256, 0, stream>>>(
        d_in[1], f_bonds_p, N_BONDS, BFDIM, FB_S, flag);

    WTab wt;
    const void* wsrc[11] = {d_in[2], d_in[3], d_in[4], d_in[7], d_in[8], d_in[9],
                            d_in[10], d_in[11], d_in[12], d_in[17], d_in[15]};
    hbf16* wdst[11] = {Wt_qa, Wt_ka, Wt_va, Wt_i, Wt_h, Wt_q, Wt_k, Wt_v, Wt_a, Wt_b, Wt_o};
    const int wK[11]  = {FDIM, FDIM, FDIM, BFDIM, HID, HID, HID, HID, HID, HID, FDIM + HID};
    const int wH[11]  = {FDIM, FDIM, FDIM, HID, HID, HID, HID, HID, HID, HID, HID};
    const int wKp[11] = {FA_S, FA_S, FA_S, FB_S, HID, HID, HID, HID, HID, HID, AI_S};
    const int wHp[11] = {192, 192, 192, HID, HID, HID, HID, HID, HID, HID, HID};
    for (int i = 0; i < 11; i++) {
        wt.src[i] = wsrc[i]; wt.dst[i] = wdst[i]; wt.K[i] = wK[i]; wt.Hout[i] = wH[i];
        wt.Kp[i] = wKp[i]; wt.total[i] = wHp[i] * wKp[i];
    }
    wt_all_kernel<<<dim3(416, 11), 256, 0, stream>>>(wt, flag);

    auto mg = [&](const float* A, int lda, const hbf16* Wt, const float* bias,
                  float* Cf, float* Cf2, int ldcf, hbf16* Cbh, hbf16* Cbl, int ldcb,
                  hbf16* CbT, int ldct, int rows, int Hout, int HoutStore, int relu) {
        dim3 grid((HoutStore + 63) / 64, rows / 64);
        mgemm_kernel<<<grid, 256, 0, stream>>>(A, lda, Wt, bias, Cf, Cf2, ldcf,
                                               Cbh, Cbl, ldcb, CbT, ldct,
                                               Hout, HoutStore, relu);
    };

    // --- atom self-attention stage ---
    mg(f_atoms_p, FA_S, Wt_qa, nullptr, buf1, nullptr, FA_S, nullptr, nullptr, 0,
       nullptr, 0, N_ATOMS, FDIM, FA_S, 0);                                     // qa
    mg(f_atoms_p, FA_S, Wt_ka, nullptr, buf2, nullptr, FA_S, nullptr, nullptr, 0,
       nullptr, 0, N_ATOMS, FDIM, FA_S, 0);                                     // ka
    mg(f_atoms_p, FA_S, Wt_va, nullptr, nullptr, nullptr, 0, nullptr, nullptr, 0,
       vTa, N_ATOMS, N_ATOMS, FDIM, 192, 0);                                    // vT
    atom_fused_kernel<<<NMOL, 256, 0, stream>>>(buf1, buf2, vTa, f_atoms_p, ln_g, ln_b, f_e);

    // --- bond init: inputs = f_bonds@Wi, msg = relu(inputs) ---
    mg(f_bonds_p, FB_S, Wt_i, nullptr, inputs, msg, HID, nullptr, nullptr, 0,
       nullptr, 0, N_BONDS, HID, HID, 0);

    P8 parts;
    parts.p[0] = buf1; parts.p[1] = buf3; parts.p[2] = buf4; parts.p[3] = pnew;
    PROJ pj;
    pj.A[0] = buf1; pj.w[0] = Wt_h; pj.outp[0] = buf2; pj.mode[0] = 2;   // dmpnn (f32)
    pj.A[1] = msg;  pj.w[1] = Wt_q; pj.outp[1] = Qb;   pj.mode[1] = 0;   // Q bf16
    pj.A[2] = msg;  pj.w[2] = Wt_k; pj.outp[2] = Kb;   pj.mode[2] = 0;   // K bf16
    pj.A[3] = msg;  pj.w[3] = Wt_v; pj.outp[3] = Vtg;  pj.mode[3] = 1;   // V^T bf16

    // --- message passing ---
    for (int d = 0; d < 3; d++) {
        gather_pre_kernel<<<N_BONDS, 256, 0, stream>>>(msg, a2b, b2a, b2revb, buf1);
        proj_kernel<<<dim3(4, N_BONDS / 64, 4), 256, 0, stream>>>(pj);
        flash_kernel<<<dim3(CS, N_BONDS / 32), 256, 0, stream>>>(Qb, Kb, Vtg, parts, ml);
        attcombine_kernel<<<N_BONDS / 32, 256, 0, stream>>>(parts, ml, Wt_a, inputs,
                                                            buf2, Walpha_w, Walpha_b, msg);
    }

    // --- readout ---
    gather_kernel<<<N_ATOMS, 256, 0, stream>>>(msg, a2b, amsg);
    concat_kernel<<<N_ATOMS, 256, 0, stream>>>(f_e, amsg, buf1);                // a_input
    mg(buf1, AI_S, Wt_o, Wo_b, buf4, nullptr, HID, Qb, Kb, HID,
       Vtg, N_ATOMS, N_ATOMS, HID, HID, 1);                                     // atom_h

    // --- pooling ---
    mg(buf4, HID, Wt_a, nullptr, buf3, nullptr, HID, nullptr, nullptr, 0,
       nullptr, 0, N_ATOMS, HID, HID, 0);                                       // hmWa
    pool_fused_kernel<<<NMOL, 256, 0, stream>>>(buf3, buf4, Qb, Kb, Vtg, Wt_b,
                                                Wb_b, d_out, flag);
}

// Round 13
// 985.263 us; speedup vs baseline: 1.3260x; 1.3260x over previous
//
#include <hip/hip_runtime.h>
#include <hip/hip_bf16.h>

typedef __hip_bfloat16 hbf16;
typedef __bf16 bf16x8 __attribute__((ext_vector_type(8)));
typedef float floatx4 __attribute__((ext_vector_type(4)));

#define N_ATOMS 4096
#define N_BONDS 8192
#define FDIM 133
#define BFDIM 147
#define HID 256
#define APM 64
#define NMOL 64
#define FA_S 160
#define FB_S 160
#define AI_S 416
#define CS 8       // flash column splits

struct P8 { float* p[8]; };
struct PROJ { const float* A[4]; const hbf16* w[4]; void* outp[4]; int mode[4]; };
struct CvtTab { const void* src[6]; float* dst[6]; int n[6]; };
struct WTab { const void* src[11]; hbf16* dst[11]; int K[11]; int Hout[11]; int Kp[11]; int total[11]; };

__device__ __forceinline__ float bcvt(hbf16 x) { return __bfloat162float(x); }

__device__ __forceinline__ float load_in(const void* src, int i, int f32flag)
{
    return f32flag ? ((const float*)src)[i] : bcvt(((const hbf16*)src)[i]);
}

__device__ __forceinline__ void split8(const float4 a0, const float4 a1,
                                       bf16x8& hi, bf16x8& lo)
{
    const float v[8] = {a0.x, a0.y, a0.z, a0.w, a1.x, a1.y, a1.z, a1.w};
    #pragma unroll
    for (int i = 0; i < 8; i++) {
        const __bf16 h = (__bf16)v[i];
        hi[i] = h;
        lo[i] = (__bf16)(v[i] - (float)h);
    }
}

// ---------------- dtype detect ----------------
__global__ void detect_kernel(const unsigned short* __restrict__ probe, int* __restrict__ flag)
{
    const int t = threadIdx.x;
    float mx = 0.f;
    for (int i = t; i < 4096; i += 64) {
        unsigned int u = ((unsigned int)probe[i]) << 16;
        float v;
        __builtin_memcpy(&v, &u, 4);
        v = fabsf(v);
        if (!(v == v)) v = 0.f;
        if (v > 1e6f) v = 1e6f;
        mx = fmaxf(mx, v);
    }
    #pragma unroll
    for (int o = 32; o > 0; o >>= 1) mx = fmaxf(mx, __shfl_xor(mx, o));
    if (t == 0) *flag = (mx > 100.f) ? 1 : 0;   // 1 = f32 data, 0 = bf16 data
}

__global__ void small_cvt_kernel(CvtTab tab, const int* __restrict__ flag)
{
    const int f32 = *flag;
    for (int s = 0; s < 6; s++)
        for (int i = threadIdx.x; i < tab.n[s]; i += 256)
            tab.dst[s][i] = load_in(tab.src[s], i, f32);
}

__global__ void cvt_pad_kernel(const void* __restrict__ src, float* __restrict__ dst,
                               int N, int K, int Kp, const int* __restrict__ flag)
{
    const int i = blockIdx.x * 256 + threadIdx.x;
    if (i >= N * Kp) return;
    const int r = i / Kp, k = i - r * Kp;
    dst[i] = (k < K) ? load_in(src, r * K + k, *flag) : 0.f;
}

__global__ void wt_all_kernel(WTab tab, const int* __restrict__ flag)
{
    const int wid = blockIdx.y;
    const int f32 = *flag;
    const int tot = tab.total[wid], Kp = tab.Kp[wid], K = tab.K[wid], Hout = tab.Hout[wid];
    hbf16* dst = tab.dst[wid];
    const void* src = tab.src[wid];
    for (int i = blockIdx.x * 256 + threadIdx.x; i < tot; i += gridDim.x * 256) {
        const int n = i / Kp, k = i - n * Kp;
        const float v = (k < K && n < Hout) ? load_in(src, k * Hout + n, f32) : 0.f;
        dst[i] = __float2bfloat16(v);
    }
}

// ---------------- bf16 MFMA GEMM, LDS-free, multi-emit ----------------
__global__ __launch_bounds__(256)
void mgemm_kernel(const float* __restrict__ A, int lda, const hbf16* __restrict__ Wt,
                  const float* __restrict__ bias,
                  float* __restrict__ Cf, float* __restrict__ Cf2, int ldcf,
                  hbf16* __restrict__ Cbh, hbf16* __restrict__ Cbl, int ldcb,
                  hbf16* __restrict__ CbT, int ldct,
                  int Hout, int HoutStore, int relu)
{
    const int t = threadIdx.x, w = t >> 6, ln = t & 63;
    const int lane16 = ln & 15, quad = ln >> 4;
    const int rb = blockIdx.y * 64 + w * 16, cb = blockIdx.x * 64;
    const floatx4 zero4 = {0.f, 0.f, 0.f, 0.f};
    floatx4 acc[4] = {zero4, zero4, zero4, zero4};
    const float* ar = A + (size_t)(rb + lane16) * lda + quad * 8;
    for (int kk = 0; kk < lda; kk += 32) {
        const float4 a0 = *(const float4*)(ar + kk);
        const float4 a1 = *(const float4*)(ar + kk + 4);
        bf16x8 af;
        af[0] = (__bf16)a0.x; af[1] = (__bf16)a0.y; af[2] = (__bf16)a0.z; af[3] = (__bf16)a0.w;
        af[4] = (__bf16)a1.x; af[5] = (__bf16)a1.y; af[6] = (__bf16)a1.z; af[7] = (__bf16)a1.w;
        #pragma unroll
        for (int nt = 0; nt < 4; nt++) {
            const bf16x8 bf =
                *(const bf16x8*)&Wt[(size_t)(cb + nt * 16 + lane16) * lda + kk + quad * 8];
            acc[nt] = __builtin_amdgcn_mfma_f32_16x16x32_bf16(af, bf, acc[nt], 0, 0, 0);
        }
    }
    #pragma unroll
    for (int nt = 0; nt < 4; nt++) {
        const int n = cb + nt * 16 + lane16;
        if (n >= HoutStore) continue;
        const bool valid = n < Hout;
        const float bv = (bias && valid) ? bias[n] : 0.f;
        #pragma unroll
        for (int r = 0; r < 4; r++) {
            const int m = rb + quad * 4 + r;
            float v = valid ? acc[nt][r] + bv : 0.f;
            if (relu) v = fmaxf(v, 0.f);
            if (Cf)  Cf[(size_t)m * ldcf + n] = v;
            if (Cf2) Cf2[(size_t)m * ldcf + n] = fmaxf(v, 0.f);
            if (Cbh) {
                const hbf16 h = __float2bfloat16(v);
                Cbh[(size_t)m * ldcb + n] = h;
                if (Cbl) Cbl[(size_t)m * ldcb + n] = __float2bfloat16(v - bcvt(h));
            }
            if (CbT) CbT[(size_t)n * ldct + m] = __float2bfloat16(v);
        }
    }
}

// ---------------- fused projections: z selects {dmpnn(f32), Q(bf16), K(bf16), V^T(bf16)} -----
__global__ __launch_bounds__(256)
void proj_kernel(PROJ p)
{
    const int z = blockIdx.z;
    const float* __restrict__ A = p.A[z];
    const hbf16* __restrict__ Wt = p.w[z];
    void* __restrict__ outp = p.outp[z];
    const int mode = p.mode[z];
    const int t = threadIdx.x, w = t >> 6, ln = t & 63;
    const int lane16 = ln & 15, quad = ln >> 4;
    const int rb = blockIdx.y * 64 + w * 16, cb = blockIdx.x * 64;
    const floatx4 zero4 = {0.f, 0.f, 0.f, 0.f};
    floatx4 acc[4] = {zero4, zero4, zero4, zero4};
    const float* ar = A + (size_t)(rb + lane16) * HID + quad * 8;
    for (int kk = 0; kk < HID; kk += 32) {
        const float4 a0 = *(const float4*)(ar + kk);
        const float4 a1 = *(const float4*)(ar + kk + 4);
        bf16x8 af;
        af[0] = (__bf16)a0.x; af[1] = (__bf16)a0.y; af[2] = (__bf16)a0.z; af[3] = (__bf16)a0.w;
        af[4] = (__bf16)a1.x; af[5] = (__bf16)a1.y; af[6] = (__bf16)a1.z; af[7] = (__bf16)a1.w;
        #pragma unroll
        for (int nt = 0; nt < 4; nt++) {
            const bf16x8 bf =
                *(const bf16x8*)&Wt[(size_t)(cb + nt * 16 + lane16) * HID + kk + quad * 8];
            acc[nt] = __builtin_amdgcn_mfma_f32_16x16x32_bf16(af, bf, acc[nt], 0, 0, 0);
        }
    }
    #pragma unroll
    for (int nt = 0; nt < 4; nt++) {
        const int n = cb + nt * 16 + lane16;
        #pragma unroll
        for (int r = 0; r < 4; r++) {
            const int m = rb + quad * 4 + r;
            const float v = acc[nt][r];
            if (mode == 2)      ((float*)outp)[(size_t)m * HID + n] = v;
            else if (mode == 0) ((hbf16*)outp)[(size_t)m * HID + n] = __float2bfloat16(v);
            else                ((hbf16*)outp)[(size_t)n * N_BONDS + m] = __float2bfloat16(v);
        }
    }
}

// ---------------- fused per-molecule atom attention + LayerNorm ----------------
__global__ __launch_bounds__(256)
void atom_fused_kernel(const float* __restrict__ qa, const float* __restrict__ ka,
                       const hbf16* __restrict__ vT, const float* __restrict__ f_atoms_p,
                       const float* __restrict__ ln_g, const float* __restrict__ ln_b,
                       float* __restrict__ f_e)
{
    __shared__ float S[64][68];
    __shared__ __bf16 P[64][72];
    __shared__ float Y[64][136];
    const int m = blockIdx.x, t = threadIdx.x;
    const int w = t >> 6, ln = t & 63;
    const int lane16 = ln & 15, quad = ln >> 4;
    const int base = m * APM;
    const floatx4 zero4 = {0.f, 0.f, 0.f, 0.f};

    {
        floatx4 acc[4] = {zero4, zero4, zero4, zero4};
        const float* arow = qa + (size_t)(base + w * 16 + lane16) * FA_S + quad * 8;
        #pragma unroll
        for (int ks = 0; ks < 5; ks++) {
            bf16x8 ah, al;
            split8(*(const float4*)(arow + ks * 32), *(const float4*)(arow + ks * 32 + 4), ah, al);
            #pragma unroll
            for (int nt = 0; nt < 4; nt++) {
                const float* brow = ka + (size_t)(base + nt * 16 + lane16) * FA_S + ks * 32 + quad * 8;
                bf16x8 bh, bl;
                split8(*(const float4*)brow, *(const float4*)(brow + 4), bh, bl);
                acc[nt] = __builtin_amdgcn_mfma_f32_16x16x32_bf16(ah, bh, acc[nt], 0, 0, 0);
                acc[nt] = __builtin_amdgcn_mfma_f32_16x16x32_bf16(al, bh, acc[nt], 0, 0, 0);
                acc[nt] = __builtin_amdgcn_mfma_f32_16x16x32_bf16(ah, bl, acc[nt], 0, 0, 0);
            }
        }
        const float scale = 1.f / sqrtf(133.f);
        #pragma unroll
        for (int nt = 0; nt < 4; nt++)
            #pragma unroll
            for (int r = 0; r < 4; r++)
                S[w * 16 + quad * 4 + r][nt * 16 + lane16] = acc[nt][r] * scale;
    }
    for (int r = w * 16; r < w * 16 + 16; r++) {
        const float x = S[r][ln];
        float mx = x;
        #pragma unroll
        for (int o = 32; o > 0; o >>= 1) mx = fmaxf(mx, __shfl_xor(mx, o));
        const float p = __expf(x - mx);
        float sm = p;
        #pragma unroll
        for (int o = 32; o > 0; o >>= 1) sm += __shfl_xor(sm, o);
        P[r][ln] = (__bf16)(p / sm);
    }
    {
        floatx4 o[9];
        #pragma unroll
        for (int i = 0; i < 9; i++) o[i] = zero4;
        #pragma unroll
        for (int ks = 0; ks < 2; ks++) {
            const bf16x8 af = *(const bf16x8*)&P[w * 16 + lane16][ks * 32 + quad * 8];
            #pragma unroll
            for (int nt = 0; nt < 9; nt++) {
                const bf16x8 bfv =
                    *(const bf16x8*)&vT[(size_t)(nt * 16 + lane16) * N_ATOMS + base + ks * 32 + quad * 8];
                o[nt] = __builtin_amdgcn_mfma_f32_16x16x32_bf16(af, bfv, o[nt], 0, 0, 0);
            }
        }
        #pragma unroll
        for (int nt = 0; nt < 9; nt++) {
            const int f = nt * 16 + lane16;
            if (f >= FDIM) continue;
            #pragma unroll
            for (int r = 0; r < 4; r++) {
                const int a = w * 16 + quad * 4 + r;
                Y[a][f] = f_atoms_p[(size_t)(base + a) * FA_S + f] + o[nt][r];
            }
        }
    }
    for (int r = w * 16; r < w * 16 + 16; r++) {
        float sum = 0.f, sq = 0.f;
        for (int f = ln; f < FDIM; f += 64) { const float v = Y[r][f]; sum += v; sq += v * v; }
        #pragma unroll
        for (int o = 32; o > 0; o >>= 1) { sum += __shfl_xor(sum, o); sq += __shfl_xor(sq, o); }
        const float mu = sum / FDIM;
        const float var = sq / FDIM - mu * mu;
        const float rstd = rsqrtf(var + 1e-5f);
        for (int f = ln; f < FDIM; f += 64) {
            const float v = (Y[r][f] - mu) * rstd;
            f_e[(size_t)(base + r) * FDIM + f] = v * ln_g[f] + ln_b[f];
        }
    }
}

// ---------------- fused per-molecule pooling ----------------
__global__ __launch_bounds__(256)
void pool_fused_kernel(const float* __restrict__ hmWa, const float* __restrict__ atom_h,
                       const hbf16* __restrict__ hm_hi, const hbf16* __restrict__ hm_lo,
                       const hbf16* __restrict__ hmT, const hbf16* __restrict__ Wtb,
                       const float* __restrict__ Wb_b, void* __restrict__ out,
                       const int* __restrict__ flag)
{
    __shared__ float S[64][68];
    __shared__ __bf16 P[64][72];
    __shared__ __bf16 att[64][264];
    const int m = blockIdx.x, t = threadIdx.x;
    const int w = t >> 6, ln = t & 63;
    const int lane16 = ln & 15, quad = ln >> 4;
    const int base = m * APM;
    const floatx4 zero4 = {0.f, 0.f, 0.f, 0.f};

    {
        floatx4 acc[4] = {zero4, zero4, zero4, zero4};
        const float* arow = hmWa + (size_t)(base + w * 16 + lane16) * HID + quad * 8;
        #pragma unroll
        for (int ks = 0; ks < 8; ks++) {
            bf16x8 ah, al;
            split8(*(const float4*)(arow + ks * 32), *(const float4*)(arow + ks * 32 + 4), ah, al);
            #pragma unroll
            for (int nt = 0; nt < 4; nt++) {
                const size_t bidx = (size_t)(base + nt * 16 + lane16) * HID + ks * 32 + quad * 8;
                const bf16x8 bh = *(const bf16x8*)&hm_hi[bidx];
                const bf16x8 bl = *(const bf16x8*)&hm_lo[bidx];
                acc[nt] = __builtin_amdgcn_mfma_f32_16x16x32_bf16(ah, bh, acc[nt], 0, 0, 0);
                acc[nt] = __builtin_amdgcn_mfma_f32_16x16x32_bf16(al, bh, acc[nt], 0, 0, 0);
                acc[nt] = __builtin_amdgcn_mfma_f32_16x16x32_bf16(ah, bl, acc[nt], 0, 0, 0);
            }
        }
        #pragma unroll
        for (int nt = 0; nt < 4; nt++)
            #pragma unroll
            for (int r = 0; r < 4; r++)
                S[w * 16 + quad * 4 + r][nt * 16 + lane16] = acc[nt][r];
    }
    for (int r = w * 16; r < w * 16 + 16; r++) {
        const float x = S[r][ln];
        float mx = x;
        #pragma unroll
        for (int o = 32; o > 0; o >>= 1) mx = fmaxf(mx, __shfl_xor(mx, o));
        const float p = __expf(x - mx);
        float sm = p;
        #pragma unroll
        for (int o = 32; o > 0; o >>= 1) sm += __shfl_xor(sm, o);
        P[r][ln] = (__bf16)(p / sm);
    }
    __syncthreads();
    {
        floatx4 o3[4][4];
        #pragma unroll
        for (int mt = 0; mt < 4; mt++)
            #pragma unroll
            for (int nt = 0; nt < 4; nt++) o3[mt][nt] = zero4;
        #pragma unroll
        for (int ks = 0; ks < 2; ks++) {
            bf16x8 af[4];
            #pragma unroll
            for (int mt = 0; mt < 4; mt++)
                af[mt] = *(const bf16x8*)&P[mt * 16 + lane16][ks * 32 + quad * 8];
            #pragma unroll
            for (int nt = 0; nt < 4; nt++) {
                const bf16x8 bfv = *(const bf16x8*)
                    &hmT[(size_t)(w * 64 + nt * 16 + lane16) * N_ATOMS + base + ks * 32 + quad * 8];
                #pragma unroll
                for (int mt = 0; mt < 4; mt++)
                    o3[mt][nt] = __builtin_amdgcn_mfma_f32_16x16x32_bf16(af[mt], bfv, o3[mt][nt], 0, 0, 0);
            }
        }
        #pragma unroll
        for (int mt = 0; mt < 4; mt++)
            #pragma unroll
            for (int nt = 0; nt < 4; nt++)
                #pragma unroll
                for (int r = 0; r < 4; r++)
                    att[mt * 16 + quad * 4 + r][w * 64 + nt * 16 + lane16] = (__bf16)o3[mt][nt][r];
    }
    __syncthreads();
    {
        floatx4 o5[4][4];
        #pragma unroll
        for (int mt = 0; mt < 4; mt++)
            #pragma unroll
            for (int nt = 0; nt < 4; nt++) o5[mt][nt] = zero4;
        #pragma unroll
        for (int ks = 0; ks < 8; ks++) {
            bf16x8 af[4];
            #pragma unroll
            for (int mt = 0; mt < 4; mt++)
                af[mt] = *(const bf16x8*)&att[mt * 16 + lane16][ks * 32 + quad * 8];
            #pragma unroll
            for (int nt = 0; nt < 4; nt++) {
                const bf16x8 bfv = *(const bf16x8*)
                    &Wtb[(size_t)(w * 64 + nt * 16 + lane16) * HID + ks * 32 + quad * 8];
                #pragma unroll
                for (int mt = 0; mt < 4; mt++)
                    o5[mt][nt] = __builtin_amdgcn_mfma_f32_16x16x32_bf16(af[mt], bfv, o5[mt][nt], 0, 0, 0);
            }
        }
        #pragma unroll
        for (int nt = 0; nt < 4; nt++) {
            const int n = w * 64 + nt * 16 + lane16;
            const float bv = Wb_b[n];
            float s = 0.f;
            #pragma unroll
            for (int mt = 0; mt < 4; mt++)
                #pragma unroll
                for (int r = 0; r < 4; r++)
                    s += fmaxf(o5[mt][nt][r] + bv, 0.f);
            s += __shfl_xor(s, 16);
            s += __shfl_xor(s, 32);
            if (quad == 0) {
                float hsum = 0.f;
                for (int a = 0; a < APM; a++)
                    hsum += atom_h[(size_t)(base + a) * HID + n];
                const float v = (s + hsum) * (1.f / 64.f);
                if (*flag) ((float*)out)[m * HID + n] = v;
                else       ((hbf16*)out)[m * HID + n] = __float2bfloat16(v);
            }
        }
    }
}

// ---------------- flash attention v8: R6-locked shape + register-prefetch pipeline ----------
// Base = R6 config (bf16, 16 rows/wave, BC=32, CS=8, swizzled LDS, (256,2)): 184us, no spill.
// R12 disproved the occupancy theory: 45% occupancy (128-bucket) ran SLOWER (295us) - the
// round's serial latency is intra-wave (staging drain + dependent chains), not TLP-hideable.
// v8 pipelines it: next K/V tile is global-loaded into VGPRs DURING compute of the current
// tile; the vmcnt drain moves to the next round's ds_write, after ~1000 cyc of overlap.
// Cost: +32 VGPR (kbuf/vbuf) -> ~124 VGPR + 64 AGPR = 188, still the <=256/2-wave bucket.
// Failure signature: WRITE >> 66MB => spill, revert to R6 body and declare plateau.
__global__ __launch_bounds__(256, 2)
void flash_kernel(const hbf16* __restrict__ Qg, const hbf16* __restrict__ Kg,
                  const hbf16* __restrict__ Vtg, P8 parts, float2* __restrict__ ml)
{
    __shared__ __align__(16) __bf16 Ks[32][256];   // XOR-swizzled: chunk c -> c ^ (row & 31)
    __shared__ __align__(16) __bf16 Vt[256][32];   // XOR-swizzled: chunk c -> c ^ (row & 3)
    __shared__ __align__(16) __bf16 Ps[4][16][40];

    const int t = threadIdx.x, w = t >> 6, ln = t & 63;
    const int lane16 = ln & 15, quad = ln >> 4;
    const int cs = blockIdx.x;
    const int rw = blockIdx.y * 64 + w * 16;
    float* __restrict__ part = parts.p[cs];

    // staging coordinates (fixed per thread)
    const int krow = t >> 2, kc = t & 3;           // K: 4 chunks of 8 bf16 per thread-row pair
    const int vrow0 = t, vc = 0;                   // V: handled in loop below

    bf16x8 qf[8];
    #pragma unroll
    for (int ks = 0; ks < 8; ks++)
        qf[ks] = *(const bf16x8*)&Qg[(size_t)(rw + lane16) * HID + ks * 32 + quad * 8];

    const floatx4 zero4 = {0.f, 0.f, 0.f, 0.f};
    floatx4 O[16];
    #pragma unroll
    for (int i = 0; i < 16; i++) O[i] = zero4;
    float mrow[4] = {-1e30f, -1e30f, -1e30f, -1e30f};
    float lrow[4] = {0.f, 0.f, 0.f, 0.f};
    const float scale = 0.0625f;  // 1/sqrt(256)

    const int cbeg = cs * (N_BONDS / CS), cend = cbeg + N_BONDS / CS;

    // prefetch buffers: this thread's 4 K-chunks and 4 V-chunks of the NEXT tile
    bf16x8 kbuf[4], vbuf[4];
    auto load_tiles = [&](int c0) {
        #pragma unroll
        for (int ii = 0; ii < 4; ii++) {
            const int idx = t + ii * 256;
            const int row = idx >> 5, c = idx & 31;
            kbuf[ii] = *(const bf16x8*)&Kg[(size_t)(c0 + row) * HID + c * 8];
        }
        #pragma unroll
        for (int ii = 0; ii < 4; ii++) {
            const int idx = t + ii * 256;
            const int row = idx >> 2, c = idx & 3;
            vbuf[ii] = *(const bf16x8*)&Vtg[(size_t)row * N_BONDS + c0 + c * 8];
        }
    };
    load_tiles(cbeg);

    for (int c0 = cbeg; c0 < cend; c0 += 32) {
        __syncthreads();
        #pragma unroll
        for (int ii = 0; ii < 4; ii++) {              // K tile 32x256 (swizzled) from regs
            const int idx = t + ii * 256;
            const int row = idx >> 5, c = idx & 31;
            *(bf16x8*)&Ks[row][(c ^ (row & 31)) * 8] = kbuf[ii];
        }
        #pragma unroll
        for (int ii = 0; ii < 4; ii++) {              // V^T tile 256x32 (swizzled) from regs
            const int idx = t + ii * 256;
            const int row = idx >> 2, c = idx & 3;
            *(bf16x8*)&Vt[row][(c ^ (row & 3)) * 8] = vbuf[ii];
        }
        __syncthreads();
        if (c0 + 32 < cend) load_tiles(c0 + 32);      // issue next-tile loads; drain at next ds_write

        floatx4 s0 = zero4, s1 = zero4;
        #pragma unroll
        for (int ks = 0; ks < 8; ks++) {
            const int ch = ks * 4 + quad;
            const bf16x8 b0 = *(bf16x8*)&Ks[lane16][(ch ^ lane16) * 8];
            const bf16x8 b1 = *(bf16x8*)&Ks[16 + lane16][(ch ^ (16 + lane16)) * 8];
            s0 = __builtin_amdgcn_mfma_f32_16x16x32_bf16(qf[ks], b0, s0, 0, 0, 0);
            s1 = __builtin_amdgcn_mfma_f32_16x16x32_bf16(qf[ks], b1, s1, 0, 0, 0);
        }
        float alpha[4];
        #pragma unroll
        for (int r = 0; r < 4; r++) {
            const float v0 = s0[r] * scale, v1 = s1[r] * scale;
            float mx = fmaxf(v0, v1);
            #pragma unroll
            for (int o = 8; o > 0; o >>= 1) mx = fmaxf(mx, __shfl_xor(mx, o));
            const float mnew = fmaxf(mrow[r], mx);
            const float p0 = __expf(v0 - mnew), p1 = __expf(v1 - mnew);
            float ps = p0 + p1;
            #pragma unroll
            for (int o = 8; o > 0; o >>= 1) ps += __shfl_xor(ps, o);
            alpha[r] = __expf(mrow[r] - mnew);
            lrow[r] = lrow[r] * alpha[r] + ps;
            mrow[r] = mnew;
            const int row = quad * 4 + r;
            Ps[w][row][lane16] = (__bf16)p0;
            Ps[w][row][16 + lane16] = (__bf16)p1;
        }
        const bool need = (alpha[0] < 1.f) | (alpha[1] < 1.f) | (alpha[2] < 1.f) | (alpha[3] < 1.f);
        if (__any(need)) {
            #pragma unroll
            for (int nt = 0; nt < 16; nt++)
                #pragma unroll
                for (int r = 0; r < 4; r++) O[nt][r] *= alpha[r];
        }
        const bf16x8 pf = *(bf16x8*)&Ps[w][lane16][quad * 8];
        #pragma unroll
        for (int nt = 0; nt < 16; nt++) {
            const int vrow = nt * 16 + lane16;
            const bf16x8 vf = *(bf16x8*)&Vt[vrow][(quad ^ (vrow & 3)) * 8];
            O[nt] = __builtin_amdgcn_mfma_f32_16x16x32_bf16(pf, vf, O[nt], 0, 0, 0);
        }
    }
    #pragma unroll
    for (int r = 0; r < 4; r++) {
        const int row = rw + quad * 4 + r;
        #pragma unroll
        for (int nt = 0; nt < 16; nt++)
            part[(size_t)row * HID + nt * 16 + lane16] = O[nt][r];
        if (lane16 == 0) ml[cs * N_BONDS + row] = make_float2(mrow[r], lrow[r]);
    }
}

// ---------------- fused: combine partials -> @Wa -> sigmoid-gate -> msg ----------------
__global__ __launch_bounds__(256)
void attcombine_kernel(P8 parts, const float2* __restrict__ ml, const hbf16* __restrict__ Wta,
                       const float* __restrict__ inputs, const float* __restrict__ dmpnn,
                       const float* __restrict__ ww, const float* __restrict__ wb,
                       float* __restrict__ msg)
{
    __shared__ __align__(16) __bf16 Av[32][264];
    __shared__ float wgtS[32][10];
    __shared__ float dotS[32][2];
    const int t = threadIdx.x, w = t >> 6, ln = t & 63;
    const int lane16 = ln & 15, quad = ln >> 4;
    const int rb = blockIdx.x * 32;
    const int mt = w & 1, nh = w >> 1;

    if (t < 32) {
        const int row = rb + t;
        float2 e[CS];
        float M = -1e30f;
        #pragma unroll
        for (int i = 0; i < CS; i++) { e[i] = ml[i * N_BONDS + row]; M = fmaxf(M, e[i].x); }
        float den = 0.f;
        #pragma unroll
        for (int i = 0; i < CS; i++) {
            const float g = __expf(e[i].x - M);
            wgtS[t][i] = g;
            den += g * e[i].y;
        }
        wgtS[t][8] = 1.f / den;
    }
    __syncthreads();
    for (int e = t; e < 32 * 64; e += 256) {
        const int row = e >> 6, c4 = (e & 63) * 4;
        const float inv = wgtS[row][8];
        float ax = 0.f, ay = 0.f, az = 0.f, aw = 0.f;
        #pragma unroll
        for (int i = 0; i < CS; i++) {
            const float g = wgtS[row][i];
            const float4 pv = *(const float4*)&parts.p[i][(size_t)(rb + row) * HID + c4];
            ax += g * pv.x; ay += g * pv.y; az += g * pv.z; aw += g * pv.w;
        }
        Av[row][c4 + 0] = (__bf16)(ax * inv);
        Av[row][c4 + 1] = (__bf16)(ay * inv);
        Av[row][c4 + 2] = (__bf16)(az * inv);
        Av[row][c4 + 3] = (__bf16)(aw * inv);
    }
    __syncthreads();

    const floatx4 zero4 = {0.f, 0.f, 0.f, 0.f};
    floatx4 acc[8];
    #pragma unroll
    for (int nt = 0; nt < 8; nt++) acc[nt] = zero4;
    #pragma unroll
    for (int ks = 0; ks < 8; ks++) {
        const bf16x8 af = *(const bf16x8*)&Av[mt * 16 + lane16][ks * 32 + quad * 8];
        #pragma unroll
        for (int nt = 0; nt < 8; nt++) {
            const bf16x8 bf = *(const bf16x8*)
                &Wta[(size_t)(nh * 128 + nt * 16 + lane16) * HID + ks * 32 + quad * 8];
            acc[nt] = __builtin_amdgcn_mfma_f32_16x16x32_bf16(af, bf, acc[nt], 0, 0, 0);
        }
    }
    float w2[8];
    #pragma unroll
    for (int nt = 0; nt < 8; nt++) w2[nt] = ww[HID + nh * 128 + nt * 16 + lane16];
    #pragma unroll
    for (int r = 0; r < 4; r++) {
        const int row = rb + mt * 16 + quad * 4 + r;
        float dot = 0.f;
        #pragma unroll
        for (int nt = 0; nt < 8; nt++) {
            const int col = nh * 128 + nt * 16 + lane16;
            dot += acc[nt][r] * w2[nt] + dmpnn[(size_t)row * HID + col] * ww[col];
        }
        #pragma unroll
        for (int o = 8; o > 0; o >>= 1) dot += __shfl_xor(dot, o);
        if (lane16 == 0) dotS[row - rb][nh] = dot;
    }
    __syncthreads();
    #pragma unroll
    for (int r = 0; r < 4; r++) {
        const int row = rb + mt * 16 + quad * 4 + r;
        const float alpha = 1.f / (1.f + __expf(-(dotS[row - rb][0] + dotS[row - rb][1] + wb[0])));
        #pragma unroll
        for (int nt = 0; nt < 8; nt++) {
            const int col = nh * 128 + nt * 16 + lane16;
            const float dv = dmpnn[(size_t)row * HID + col];
            const float v = inputs[(size_t)row * HID + col] + alpha * dv + (1.f - alpha) * acc[nt][r];
            msg[(size_t)row * HID + col] = fmaxf(v, 0.f);
        }
    }
}

// ---------------- small fused kernels ----------------
__global__ void gather_kernel(const float* __restrict__ msg, const int* __restrict__ a2b,
                              float* __restrict__ amsg)
{
    const int a = blockIdx.x, h = threadIdx.x;
    float s = 0.f;
    #pragma unroll
    for (int i = 0; i < 6; i++) {
        const int b = a2b[a * 6 + i];
        s += msg[(size_t)b * HID + h];
    }
    amsg[(size_t)a * HID + h] = s;
}

__global__ void gather_pre_kernel(const float* __restrict__ msg, const int* __restrict__ a2b,
                                  const int* __restrict__ b2a, const int* __restrict__ b2revb,
                                  float* __restrict__ pre)
{
    const int b = blockIdx.x, h = threadIdx.x;
    const int a = b2a[b];
    float s = -msg[(size_t)b2revb[b] * HID + h];
    #pragma unroll
    for (int i = 0; i < 6; i++)
        s += msg[(size_t)a2b[a * 6 + i] * HID + h];
    pre[(size_t)b * HID + h] = s;
}

__global__ void concat_kernel(const float* __restrict__ fe, const float* __restrict__ amsg,
                              float* __restrict__ ai)
{
    const int a = blockIdx.x, t = threadIdx.x;
    for (int f = t; f < FDIM; f += 256) ai[(size_t)a * AI_S + f] = fe[(size_t)a * FDIM + f];
    for (int h = t; h < HID; h += 256) ai[(size_t)a * AI_S + FDIM + h] = amsg[(size_t)a * HID + h];
    for (int z = t; z < AI_S - FDIM - HID; z += 256) ai[(size_t)a * AI_S + FDIM + HID + z] = 0.f;
}

// ---------------- launch ----------------
extern "C" void kernel_launch(void* const* d_in, const int* in_sizes, int n_in,
                              void* d_out, int out_size, void* d_ws, size_t ws_size,
                              hipStream_t stream)
{
    const int* a2b    = (const int*)d_in[19];
    const int* b2a    = (const int*)d_in[20];
    const int* b2revb = (const int*)d_in[21];

    float* ws = (float*)d_ws;
    size_t off = 0;
    auto alloc = [&](size_t n) { float* p = ws + off; off += (n + 63) & ~(size_t)63; return p; };
    int* flag = (int*)alloc(64);

    float* ln_g     = alloc(FDIM);
    float* ln_b     = alloc(FDIM);
    float* Walpha_w = alloc(2 * HID);
    float* Walpha_b = alloc(64);
    float* Wo_b     = alloc(HID);
    float* Wb_b     = alloc(HID);
    float* f_atoms_p = alloc((size_t)N_ATOMS * FA_S);
    float* f_bonds_p = alloc((size_t)N_BONDS * FB_S);
    auto balloc = [&](size_t n) { return (hbf16*)alloc((n + 1) / 2); };
    hbf16* Wt_qa = balloc((size_t)192 * FA_S);
    hbf16* Wt_ka = balloc((size_t)192 * FA_S);
    hbf16* Wt_va = balloc((size_t)192 * FA_S);
    hbf16* Wt_i  = balloc((size_t)HID * FB_S);
    hbf16* Wt_h  = balloc((size_t)HID * HID);
    hbf16* Wt_q  = balloc((size_t)HID * HID);
    hbf16* Wt_k  = balloc((size_t)HID * HID);
    hbf16* Wt_v  = balloc((size_t)HID * HID);
    hbf16* Wt_a  = balloc((size_t)HID * HID);
    hbf16* Wt_b  = balloc((size_t)HID * HID);
    hbf16* Wt_o  = balloc((size_t)HID * AI_S);

    float* f_e    = alloc((size_t)N_ATOMS * FDIM);
    float* inputs = alloc((size_t)N_BONDS * HID);
    float* msg    = alloc((size_t)N_BONDS * HID);
    float* buf1   = alloc((size_t)N_BONDS * HID);   // qa | pre | part0 | a_input
    float* buf2   = alloc((size_t)N_BONDS * HID);   // ka | dmpnn
    float* buf3   = alloc((size_t)N_BONDS * HID);   // vT | part1 | hmWa
    float* buf4   = alloc((size_t)N_BONDS * HID);   // part2 | atom_h
    float* pnew   = alloc((size_t)N_BONDS * HID);   // part3
    float* pext0  = alloc((size_t)N_BONDS * HID);
    float* pext1  = alloc((size_t)N_BONDS * HID);
    float* pext2  = alloc((size_t)N_BONDS * HID);
    float* pext3  = alloc((size_t)N_BONDS * HID);
    float* amsg   = alloc((size_t)N_ATOMS * HID);
    float2* ml    = (float2*)alloc((size_t)CS * N_BONDS * 2);
    hbf16* Qb  = balloc((size_t)N_BONDS * HID);     // later: hm_hi
    hbf16* Kb  = balloc((size_t)N_BONDS * HID);     // later: hm_lo
    hbf16* Vtg = balloc((size_t)N_BONDS * HID);     // later: hmT
    hbf16* vTa = (hbf16*)buf3;                       // atom V^T [192][4096]

    detect_kernel<<<1, 64, 0, stream>>>((const unsigned short*)d_in[1], flag);

    CvtTab ct;
    ct.src[0] = d_in[5];  ct.dst[0] = ln_g;     ct.n[0] = FDIM;
    ct.src[1] = d_in[6];  ct.dst[1] = ln_b;     ct.n[1] = FDIM;
    ct.src[2] = d_in[13]; ct.dst[2] = Walpha_w; ct.n[2] = 2 * HID;
    ct.src[3] = d_in[14]; ct.dst[3] = Walpha_b; ct.n[3] = 1;
    ct.src[4] = d_in[16]; ct.dst[4] = Wo_b;     ct.n[4] = HID;
    ct.src[5] = d_in[18]; ct.dst[5] = Wb_b;     ct.n[5] = HID;
    small_cvt_kernel<<<1, 256, 0, stream>>>(ct, flag);

    cvt_pad_kernel<<<(N_ATOMS * FA_S + 255) / 256, 256, 0, stream>>>(
        d_in[0], f_atoms_p, N_ATOMS, FDIM, FA_S, flag);
    cvt_pad_kernel<<<(N_BONDS * FB_S + 255) / 256, 256, 0, stream>>>(
        d_in[1], f_bonds_p, N_BONDS, BFDIM, FB_S, flag);

    WTab wt;
    const void* wsrc[11] = {d_in[2], d_in[3], d_in[4], d_in[7], d_in[8], d_in[9],
                            d_in[10], d_in[11], d_in[12], d_in[17], d_in[15]};
    hbf16* wdst[11] = {Wt_qa, Wt_ka, Wt_va, Wt_i, Wt_h, Wt_q, Wt_k, Wt_v, Wt_a, Wt_b, Wt_o};
    const int wK[11]  = {FDIM, FDIM, FDIM, BFDIM, HID, HID, HID, HID, HID, HID, FDIM + HID};
    const int wH[11]  = {FDIM, FDIM, FDIM, HID, HID, HID, HID, HID, HID, HID, HID};
    const int wKp[11] = {FA_S, FA_S, FA_S, FB_S, HID, HID, HID, HID, HID, HID, AI_S};
    const int wHp[11] = {192, 192, 192, HID, HID, HID, HID, HID, HID, HID, HID};
    for (int i = 0; i < 11; i++) {
        wt.src[i] = wsrc[i]; wt.dst[i] = wdst[i]; wt.K[i] = wK[i]; wt.Hout[i] = wH[i];
        wt.Kp[i] = wKp[i]; wt.total[i] = wHp[i] * wKp[i];
    }
    wt_all_kernel<<<dim3(416, 11), 256, 0, stream>>>(wt, flag);

    auto mg = [&](const float* A, int lda, const hbf16* Wt, const float* bias,
                  float* Cf, float* Cf2, int ldcf, hbf16* Cbh, hbf16* Cbl, int ldcb,
                  hbf16* CbT, int ldct, int rows, int Hout, int HoutStore, int relu) {
        dim3 grid((HoutStore + 63) / 64, rows / 64);
        mgemm_kernel<<<grid, 256, 0, stream>>>(A, lda, Wt, bias, Cf, Cf2, ldcf,
                                               Cbh, Cbl, ldcb, CbT, ldct,
                                               Hout, HoutStore, relu);
    };

    // --- atom self-attention stage ---
    mg(f_atoms_p, FA_S, Wt_qa, nullptr, buf1, nullptr, FA_S, nullptr, nullptr, 0,
       nullptr, 0, N_ATOMS, FDIM, FA_S, 0);                                     // qa
    mg(f_atoms_p, FA_S, Wt_ka, nullptr, buf2, nullptr, FA_S, nullptr, nullptr, 0,
       nullptr, 0, N_ATOMS, FDIM, FA_S, 0);                                     // ka
    mg(f_atoms_p, FA_S, Wt_va, nullptr, nullptr, nullptr, 0, nullptr, nullptr, 0,
       vTa, N_ATOMS, N_ATOMS, FDIM, 192, 0);                                    // vT
    atom_fused_kernel<<<NMOL, 256, 0, stream>>>(buf1, buf2, vTa, f_atoms_p, ln_g, ln_b, f_e);

    // --- bond init: inputs = f_bonds@Wi, msg = relu(inputs) ---
    mg(f_bonds_p, FB_S, Wt_i, nullptr, inputs, msg, HID, nullptr, nullptr, 0,
       nullptr, 0, N_BONDS, HID, HID, 0);

    P8 parts;
    parts.p[0] = buf1; parts.p[1] = buf3; parts.p[2] = buf4; parts.p[3] = pnew;
    parts.p[4] = pext0; parts.p[5] = pext1; parts.p[6] = pext2; parts.p[7] = pext3;
    PROJ pj;
    pj.A[0] = buf1; pj.w[0] = Wt_h; pj.outp[0] = buf2; pj.mode[0] = 2;   // dmpnn (f32)
    pj.A[1] = msg;  pj.w[1] = Wt_q; pj.outp[1] = Qb;   pj.mode[1] = 0;   // Q bf16
    pj.A[2] = msg;  pj.w[2] = Wt_k; pj.outp[2] = Kb;   pj.mode[2] = 0;   // K bf16
    pj.A[3] = msg;  pj.w[3] = Wt_v; pj.outp[3] = Vtg;  pj.mode[3] = 1;   // V^T bf16

    // --- message passing ---
    for (int d = 0; d < 3; d++) {
        gather_pre_kernel<<<N_BONDS, 256, 0, stream>>>(msg, a2b, b2a, b2revb, buf1);
        proj_kernel<<<dim3(4, N_BONDS / 64, 4), 256, 0, stream>>>(pj);
        flash_kernel<<<dim3(CS, N_BONDS / 64), 256, 0, stream>>>(Qb, Kb, Vtg, parts, ml);
        attcombine_kernel<<<N_BONDS / 32, 256, 0, stream>>>(parts, ml, Wt_a, inputs,
                                                            buf2, Walpha_w, Walpha_b, msg);
    }

    // --- readout ---
    gather_kernel<<<N_ATOMS, 256, 0, stream>>>(msg, a2b, amsg);
    concat_kernel<<<N_ATOMS, 256, 0, stream>>>(f_e, amsg, buf1);                // a_input
    mg(buf1, AI_S, Wt_o, Wo_b, buf4, nullptr, HID, Qb, Kb, HID,
       Vtg, N_ATOMS, N_ATOMS, HID, HID, 1);                                     // atom_h

    // --- pooling ---
    mg(buf4, HID, Wt_a, nullptr, buf3, nullptr, HID, nullptr, nullptr, 0,
       nullptr, 0, N_ATOMS, HID, HID, 0);                                       // hmWa
    pool_fused_kernel<<<NMOL, 256, 0, stream>>>(buf3, buf4, Qb, Kb, Vtg, Wt_b,
                                                Wb_b, d_out, flag);
}

// Round 14
// 974.777 us; speedup vs baseline: 1.3402x; 1.0108x over previous
//
#include <hip/hip_runtime.h>
#include <hip/hip_bf16.h>

typedef __hip_bfloat16 hbf16;
typedef __bf16 bf16x8 __attribute__((ext_vector_type(8)));
typedef __bf16 bf16x4 __attribute__((ext_vector_type(4)));
typedef float floatx4 __attribute__((ext_vector_type(4)));

#define N_ATOMS 4096
#define N_BONDS 8192
#define FDIM 133
#define BFDIM 147
#define HID 256
#define APM 64
#define NMOL 64
#define FA_S 160
#define FB_S 160
#define AI_S 416
#define CS 8       // flash column splits

struct P8 { hbf16* p[8]; };   // bf16 partials (R14: halves flash WRITE 66->33MB)
struct PROJ { const float* A[4]; const hbf16* w[4]; void* outp[4]; int mode[4]; };
struct CvtTab { const void* src[6]; float* dst[6]; int n[6]; };
struct WTab { const void* src[11]; hbf16* dst[11]; int K[11]; int Hout[11]; int Kp[11]; int total[11]; };

__device__ __forceinline__ float bcvt(hbf16 x) { return __bfloat162float(x); }

__device__ __forceinline__ float load_in(const void* src, int i, int f32flag)
{
    return f32flag ? ((const float*)src)[i] : bcvt(((const hbf16*)src)[i]);
}

__device__ __forceinline__ void split8(const float4 a0, const float4 a1,
                                       bf16x8& hi, bf16x8& lo)
{
    const float v[8] = {a0.x, a0.y, a0.z, a0.w, a1.x, a1.y, a1.z, a1.w};
    #pragma unroll
    for (int i = 0; i < 8; i++) {
        const __bf16 h = (__bf16)v[i];
        hi[i] = h;
        lo[i] = (__bf16)(v[i] - (float)h);
    }
}

// ---------------- dtype detect ----------------
__global__ void detect_kernel(const unsigned short* __restrict__ probe, int* __restrict__ flag)
{
    const int t = threadIdx.x;
    float mx = 0.f;
    for (int i = t; i < 4096; i += 64) {
        unsigned int u = ((unsigned int)probe[i]) << 16;
        float v;
        __builtin_memcpy(&v, &u, 4);
        v = fabsf(v);
        if (!(v == v)) v = 0.f;
        if (v > 1e6f) v = 1e6f;
        mx = fmaxf(mx, v);
    }
    #pragma unroll
    for (int o = 32; o > 0; o >>= 1) mx = fmaxf(mx, __shfl_xor(mx, o));
    if (t == 0) *flag = (mx > 100.f) ? 1 : 0;   // 1 = f32 data, 0 = bf16 data
}

__global__ void small_cvt_kernel(CvtTab tab, const int* __restrict__ flag)
{
    const int f32 = *flag;
    for (int s = 0; s < 6; s++)
        for (int i = threadIdx.x; i < tab.n[s]; i += 256)
            tab.dst[s][i] = load_in(tab.src[s], i, f32);
}

__global__ void cvt_pad_kernel(const void* __restrict__ src, float* __restrict__ dst,
                               int N, int K, int Kp, const int* __restrict__ flag)
{
    const int i = blockIdx.x * 256 + threadIdx.x;
    if (i >= N * Kp) return;
    const int r = i / Kp, k = i - r * Kp;
    dst[i] = (k < K) ? load_in(src, r * K + k, *flag) : 0.f;
}

__global__ void wt_all_kernel(WTab tab, const int* __restrict__ flag)
{
    const int wid = blockIdx.y;
    const int f32 = *flag;
    const int tot = tab.total[wid], Kp = tab.Kp[wid], K = tab.K[wid], Hout = tab.Hout[wid];
    hbf16* dst = tab.dst[wid];
    const void* src = tab.src[wid];
    for (int i = blockIdx.x * 256 + threadIdx.x; i < tot; i += gridDim.x * 256) {
        const int n = i / Kp, k = i - n * Kp;
        const float v = (k < K && n < Hout) ? load_in(src, k * Hout + n, f32) : 0.f;
        dst[i] = __float2bfloat16(v);
    }
}

// ---------------- bf16 MFMA GEMM, LDS-free, multi-emit ----------------
__global__ __launch_bounds__(256)
void mgemm_kernel(const float* __restrict__ A, int lda, const hbf16* __restrict__ Wt,
                  const float* __restrict__ bias,
                  float* __restrict__ Cf, float* __restrict__ Cf2, int ldcf,
                  hbf16* __restrict__ Cbh, hbf16* __restrict__ Cbl, int ldcb,
                  hbf16* __restrict__ CbT, int ldct,
                  int Hout, int HoutStore, int relu)
{
    const int t = threadIdx.x, w = t >> 6, ln = t & 63;
    const int lane16 = ln & 15, quad = ln >> 4;
    const int rb = blockIdx.y * 64 + w * 16, cb = blockIdx.x * 64;
    const floatx4 zero4 = {0.f, 0.f, 0.f, 0.f};
    floatx4 acc[4] = {zero4, zero4, zero4, zero4};
    const float* ar = A + (size_t)(rb + lane16) * lda + quad * 8;
    for (int kk = 0; kk < lda; kk += 32) {
        const float4 a0 = *(const float4*)(ar + kk);
        const float4 a1 = *(const float4*)(ar + kk + 4);
        bf16x8 af;
        af[0] = (__bf16)a0.x; af[1] = (__bf16)a0.y; af[2] = (__bf16)a0.z; af[3] = (__bf16)a0.w;
        af[4] = (__bf16)a1.x; af[5] = (__bf16)a1.y; af[6] = (__bf16)a1.z; af[7] = (__bf16)a1.w;
        #pragma unroll
        for (int nt = 0; nt < 4; nt++) {
            const bf16x8 bf =
                *(const bf16x8*)&Wt[(size_t)(cb + nt * 16 + lane16) * lda + kk + quad * 8];
            acc[nt] = __builtin_amdgcn_mfma_f32_16x16x32_bf16(af, bf, acc[nt], 0, 0, 0);
        }
    }
    #pragma unroll
    for (int nt = 0; nt < 4; nt++) {
        const int n = cb + nt * 16 + lane16;
        if (n >= HoutStore) continue;
        const bool valid = n < Hout;
        const float bv = (bias && valid) ? bias[n] : 0.f;
        #pragma unroll
        for (int r = 0; r < 4; r++) {
            const int m = rb + quad * 4 + r;
            float v = valid ? acc[nt][r] + bv : 0.f;
            if (relu) v = fmaxf(v, 0.f);
            if (Cf)  Cf[(size_t)m * ldcf + n] = v;
            if (Cf2) Cf2[(size_t)m * ldcf + n] = fmaxf(v, 0.f);
            if (Cbh) {
                const hbf16 h = __float2bfloat16(v);
                Cbh[(size_t)m * ldcb + n] = h;
                if (Cbl) Cbl[(size_t)m * ldcb + n] = __float2bfloat16(v - bcvt(h));
            }
            if (CbT) CbT[(size_t)n * ldct + m] = __float2bfloat16(v);
        }
    }
}

// ---------------- fused projections: z selects {dmpnn(f32), Q(bf16), K(bf16), V^T(bf16)} -----
__global__ __launch_bounds__(256)
void proj_kernel(PROJ p)
{
    const int z = blockIdx.z;
    const float* __restrict__ A = p.A[z];
    const hbf16* __restrict__ Wt = p.w[z];
    void* __restrict__ outp = p.outp[z];
    const int mode = p.mode[z];
    const int t = threadIdx.x, w = t >> 6, ln = t & 63;
    const int lane16 = ln & 15, quad = ln >> 4;
    const int rb = blockIdx.y * 64 + w * 16, cb = blockIdx.x * 64;
    const floatx4 zero4 = {0.f, 0.f, 0.f, 0.f};
    floatx4 acc[4] = {zero4, zero4, zero4, zero4};
    const float* ar = A + (size_t)(rb + lane16) * HID + quad * 8;
    for (int kk = 0; kk < HID; kk += 32) {
        const float4 a0 = *(const float4*)(ar + kk);
        const float4 a1 = *(const float4*)(ar + kk + 4);
        bf16x8 af;
        af[0] = (__bf16)a0.x; af[1] = (__bf16)a0.y; af[2] = (__bf16)a0.z; af[3] = (__bf16)a0.w;
        af[4] = (__bf16)a1.x; af[5] = (__bf16)a1.y; af[6] = (__bf16)a1.z; af[7] = (__bf16)a1.w;
        #pragma unroll
        for (int nt = 0; nt < 4; nt++) {
            const bf16x8 bf =
                *(const bf16x8*)&Wt[(size_t)(cb + nt * 16 + lane16) * HID + kk + quad * 8];
            acc[nt] = __builtin_amdgcn_mfma_f32_16x16x32_bf16(af, bf, acc[nt], 0, 0, 0);
        }
    }
    #pragma unroll
    for (int nt = 0; nt < 4; nt++) {
        const int n = cb + nt * 16 + lane16;
        #pragma unroll
        for (int r = 0; r < 4; r++) {
            const int m = rb + quad * 4 + r;
            const float v = acc[nt][r];
            if (mode == 2)      ((float*)outp)[(size_t)m * HID + n] = v;
            else if (mode == 0) ((hbf16*)outp)[(size_t)m * HID + n] = __float2bfloat16(v);
            else                ((hbf16*)outp)[(size_t)n * N_BONDS + m] = __float2bfloat16(v);
        }
    }
}

// ---------------- fused per-molecule atom attention + LayerNorm ----------------
__global__ __launch_bounds__(256)
void atom_fused_kernel(const float* __restrict__ qa, const float* __restrict__ ka,
                       const hbf16* __restrict__ vT, const float* __restrict__ f_atoms_p,
                       const float* __restrict__ ln_g, const float* __restrict__ ln_b,
                       float* __restrict__ f_e)
{
    __shared__ float S[64][68];
    __shared__ __bf16 P[64][72];
    __shared__ float Y[64][136];
    const int m = blockIdx.x, t = threadIdx.x;
    const int w = t >> 6, ln = t & 63;
    const int lane16 = ln & 15, quad = ln >> 4;
    const int base = m * APM;
    const floatx4 zero4 = {0.f, 0.f, 0.f, 0.f};

    {
        floatx4 acc[4] = {zero4, zero4, zero4, zero4};
        const float* arow = qa + (size_t)(base + w * 16 + lane16) * FA_S + quad * 8;
        #pragma unroll
        for (int ks = 0; ks < 5; ks++) {
            bf16x8 ah, al;
            split8(*(const float4*)(arow + ks * 32), *(const float4*)(arow + ks * 32 + 4), ah, al);
            #pragma unroll
            for (int nt = 0; nt < 4; nt++) {
                const float* brow = ka + (size_t)(base + nt * 16 + lane16) * FA_S + ks * 32 + quad * 8;
                bf16x8 bh, bl;
                split8(*(const float4*)brow, *(const float4*)(brow + 4), bh, bl);
                acc[nt] = __builtin_amdgcn_mfma_f32_16x16x32_bf16(ah, bh, acc[nt], 0, 0, 0);
                acc[nt] = __builtin_amdgcn_mfma_f32_16x16x32_bf16(al, bh, acc[nt], 0, 0, 0);
                acc[nt] = __builtin_amdgcn_mfma_f32_16x16x32_bf16(ah, bl, acc[nt], 0, 0, 0);
            }
        }
        const float scale = 1.f / sqrtf(133.f);
        #pragma unroll
        for (int nt = 0; nt < 4; nt++)
            #pragma unroll
            for (int r = 0; r < 4; r++)
                S[w * 16 + quad * 4 + r][nt * 16 + lane16] = acc[nt][r] * scale;
    }
    for (int r = w * 16; r < w * 16 + 16; r++) {
        const float x = S[r][ln];
        float mx = x;
        #pragma unroll
        for (int o = 32; o > 0; o >>= 1) mx = fmaxf(mx, __shfl_xor(mx, o));
        const float p = __expf(x - mx);
        float sm = p;
        #pragma unroll
        for (int o = 32; o > 0; o >>= 1) sm += __shfl_xor(sm, o);
        P[r][ln] = (__bf16)(p / sm);
    }
    {
        floatx4 o[9];
        #pragma unroll
        for (int i = 0; i < 9; i++) o[i] = zero4;
        #pragma unroll
        for (int ks = 0; ks < 2; ks++) {
            const bf16x8 af = *(const bf16x8*)&P[w * 16 + lane16][ks * 32 + quad * 8];
            #pragma unroll
            for (int nt = 0; nt < 9; nt++) {
                const bf16x8 bfv =
                    *(const bf16x8*)&vT[(size_t)(nt * 16 + lane16) * N_ATOMS + base + ks * 32 + quad * 8];
                o[nt] = __builtin_amdgcn_mfma_f32_16x16x32_bf16(af, bfv, o[nt], 0, 0, 0);
            }
        }
        #pragma unroll
        for (int nt = 0; nt < 9; nt++) {
            const int f = nt * 16 + lane16;
            if (f >= FDIM) continue;
            #pragma unroll
            for (int r = 0; r < 4; r++) {
                const int a = w * 16 + quad * 4 + r;
                Y[a][f] = f_atoms_p[(size_t)(base + a) * FA_S + f] + o[nt][r];
            }
        }
    }
    for (int r = w * 16; r < w * 16 + 16; r++) {
        float sum = 0.f, sq = 0.f;
        for (int f = ln; f < FDIM; f += 64) { const float v = Y[r][f]; sum += v; sq += v * v; }
        #pragma unroll
        for (int o = 32; o > 0; o >>= 1) { sum += __shfl_xor(sum, o); sq += __shfl_xor(sq, o); }
        const float mu = sum / FDIM;
        const float var = sq / FDIM - mu * mu;
        const float rstd = rsqrtf(var + 1e-5f);
        for (int f = ln; f < FDIM; f += 64) {
            const float v = (Y[r][f] - mu) * rstd;
            f_e[(size_t)(base + r) * FDIM + f] = v * ln_g[f] + ln_b[f];
        }
    }
}

// ---------------- fused per-molecule pooling ----------------
__global__ __launch_bounds__(256)
void pool_fused_kernel(const float* __restrict__ hmWa, const float* __restrict__ atom_h,
                       const hbf16* __restrict__ hm_hi, const hbf16* __restrict__ hm_lo,
                       const hbf16* __restrict__ hmT, const hbf16* __restrict__ Wtb,
                       const float* __restrict__ Wb_b, void* __restrict__ out,
                       const int* __restrict__ flag)
{
    __shared__ float S[64][68];
    __shared__ __bf16 P[64][72];
    __shared__ __bf16 att[64][264];
    const int m = blockIdx.x, t = threadIdx.x;
    const int w = t >> 6, ln = t & 63;
    const int lane16 = ln & 15, quad = ln >> 4;
    const int base = m * APM;
    const floatx4 zero4 = {0.f, 0.f, 0.f, 0.f};

    {
        floatx4 acc[4] = {zero4, zero4, zero4, zero4};
        const float* arow = hmWa + (size_t)(base + w * 16 + lane16) * HID + quad * 8;
        #pragma unroll
        for (int ks = 0; ks < 8; ks++) {
            bf16x8 ah, al;
            split8(*(const float4*)(arow + ks * 32), *(const float4*)(arow + ks * 32 + 4), ah, al);
            #pragma unroll
            for (int nt = 0; nt < 4; nt++) {
                const size_t bidx = (size_t)(base + nt * 16 + lane16) * HID + ks * 32 + quad * 8;
                const bf16x8 bh = *(const bf16x8*)&hm_hi[bidx];
                const bf16x8 bl = *(const bf16x8*)&hm_lo[bidx];
                acc[nt] = __builtin_amdgcn_mfma_f32_16x16x32_bf16(ah, bh, acc[nt], 0, 0, 0);
                acc[nt] = __builtin_amdgcn_mfma_f32_16x16x32_bf16(al, bh, acc[nt], 0, 0, 0);
                acc[nt] = __builtin_amdgcn_mfma_f32_16x16x32_bf16(ah, bl, acc[nt], 0, 0, 0);
            }
        }
        #pragma unroll
        for (int nt = 0; nt < 4; nt++)
            #pragma unroll
            for (int r = 0; r < 4; r++)
                S[w * 16 + quad * 4 + r][nt * 16 + lane16] = acc[nt][r];
    }
    for (int r = w * 16; r < w * 16 + 16; r++) {
        const float x = S[r][ln];
        float mx = x;
        #pragma unroll
        for (int o = 32; o > 0; o >>= 1) mx = fmaxf(mx, __shfl_xor(mx, o));
        const float p = __expf(x - mx);
        float sm = p;
        #pragma unroll
        for (int o = 32; o > 0; o >>= 1) sm += __shfl_xor(sm, o);
        P[r][ln] = (__bf16)(p / sm);
    }
    __syncthreads();
    {
        floatx4 o3[4][4];
        #pragma unroll
        for (int mt = 0; mt < 4; mt++)
            #pragma unroll
            for (int nt = 0; nt < 4; nt++) o3[mt][nt] = zero4;
        #pragma unroll
        for (int ks = 0; ks < 2; ks++) {
            bf16x8 af[4];
            #pragma unroll
            for (int mt = 0; mt < 4; mt++)
                af[mt] = *(const bf16x8*)&P[mt * 16 + lane16][ks * 32 + quad * 8];
            #pragma unroll
            for (int nt = 0; nt < 4; nt++) {
                const bf16x8 bfv = *(const bf16x8*)
                    &hmT[(size_t)(w * 64 + nt * 16 + lane16) * N_ATOMS + base + ks * 32 + quad * 8];
                #pragma unroll
                for (int mt = 0; mt < 4; mt++)
                    o3[mt][nt] = __builtin_amdgcn_mfma_f32_16x16x32_bf16(af[mt], bfv, o3[mt][nt], 0, 0, 0);
            }
        }
        #pragma unroll
        for (int mt = 0; mt < 4; mt++)
            #pragma unroll
            for (int nt = 0; nt < 4; nt++)
                #pragma unroll
                for (int r = 0; r < 4; r++)
                    att[mt * 16 + quad * 4 + r][w * 64 + nt * 16 + lane16] = (__bf16)o3[mt][nt][r];
    }
    __syncthreads();
    {
        floatx4 o5[4][4];
        #pragma unroll
        for (int mt = 0; mt < 4; mt++)
            #pragma unroll
            for (int nt = 0; nt < 4; nt++) o5[mt][nt] = zero4;
        #pragma unroll
        for (int ks = 0; ks < 8; ks++) {
            bf16x8 af[4];
            #pragma unroll
            for (int mt = 0; mt < 4; mt++)
                af[mt] = *(const bf16x8*)&att[mt * 16 + lane16][ks * 32 + quad * 8];
            #pragma unroll
            for (int nt = 0; nt < 4; nt++) {
                const bf16x8 bfv = *(const bf16x8*)
                    &Wtb[(size_t)(w * 64 + nt * 16 + lane16) * HID + ks * 32 + quad * 8];
                #pragma unroll
                for (int mt = 0; mt < 4; mt++)
                    o5[mt][nt] = __builtin_amdgcn_mfma_f32_16x16x32_bf16(af[mt], bfv, o5[mt][nt], 0, 0, 0);
            }
        }
        #pragma unroll
        for (int nt = 0; nt < 4; nt++) {
            const int n = w * 64 + nt * 16 + lane16;
            const float bv = Wb_b[n];
            float s = 0.f;
            #pragma unroll
            for (int mt = 0; mt < 4; mt++)
                #pragma unroll
                for (int r = 0; r < 4; r++)
                    s += fmaxf(o5[mt][nt][r] + bv, 0.f);
            s += __shfl_xor(s, 16);
            s += __shfl_xor(s, 32);
            if (quad == 0) {
                float hsum = 0.f;
                for (int a = 0; a < APM; a++)
                    hsum += atom_h[(size_t)(base + a) * HID + n];
                const float v = (s + hsum) * (1.f / 64.f);
                if (*flag) ((float*)out)[m * HID + n] = v;
                else       ((hbf16*)out)[m * HID + n] = __float2bfloat16(v);
            }
        }
    }
}

// ---------------- flash attention v9: R13 pipeline + bf16 partials ----------------
// R13 (register-prefetch, 179us, VGPR 104, no spill) is the locked base. v9's single
// change: partial-O stores in bf16 (WRITE 66->33MB). attcombine casts att_v to bf16
// anyway before the Wa MFMA, so the f32 partial precision was being discarded one
// step later; the extra rounding is ~0.4% rel on pre-combine values.
__global__ __launch_bounds__(256, 2)
void flash_kernel(const hbf16* __restrict__ Qg, const hbf16* __restrict__ Kg,
                  const hbf16* __restrict__ Vtg, P8 parts, float2* __restrict__ ml)
{
    __shared__ __align__(16) __bf16 Ks[32][256];   // XOR-swizzled: chunk c -> c ^ (row & 31)
    __shared__ __align__(16) __bf16 Vt[256][32];   // XOR-swizzled: chunk c -> c ^ (row & 3)
    __shared__ __align__(16) __bf16 Ps[4][16][40];

    const int t = threadIdx.x, w = t >> 6, ln = t & 63;
    const int lane16 = ln & 15, quad = ln >> 4;
    const int cs = blockIdx.x;
    const int rw = blockIdx.y * 64 + w * 16;
    hbf16* __restrict__ part = parts.p[cs];

    bf16x8 qf[8];
    #pragma unroll
    for (int ks = 0; ks < 8; ks++)
        qf[ks] = *(const bf16x8*)&Qg[(size_t)(rw + lane16) * HID + ks * 32 + quad * 8];

    const floatx4 zero4 = {0.f, 0.f, 0.f, 0.f};
    floatx4 O[16];
    #pragma unroll
    for (int i = 0; i < 16; i++) O[i] = zero4;
    float mrow[4] = {-1e30f, -1e30f, -1e30f, -1e30f};
    float lrow[4] = {0.f, 0.f, 0.f, 0.f};
    const float scale = 0.0625f;  // 1/sqrt(256)

    const int cbeg = cs * (N_BONDS / CS), cend = cbeg + N_BONDS / CS;

    // register prefetch of next K/V tile (R13: overlaps global latency with compute)
    bf16x8 kbuf[4], vbuf[4];
    auto load_tiles = [&](int c0) {
        #pragma unroll
        for (int ii = 0; ii < 4; ii++) {
            const int idx = t + ii * 256;
            const int row = idx >> 5, c = idx & 31;
            kbuf[ii] = *(const bf16x8*)&Kg[(size_t)(c0 + row) * HID + c * 8];
        }
        #pragma unroll
        for (int ii = 0; ii < 4; ii++) {
            const int idx = t + ii * 256;
            const int row = idx >> 2, c = idx & 3;
            vbuf[ii] = *(const bf16x8*)&Vtg[(size_t)row * N_BONDS + c0 + c * 8];
        }
    };
    load_tiles(cbeg);

    for (int c0 = cbeg; c0 < cend; c0 += 32) {
        __syncthreads();
        #pragma unroll
        for (int ii = 0; ii < 4; ii++) {              // K tile 32x256 (swizzled) from regs
            const int idx = t + ii * 256;
            const int row = idx >> 5, c = idx & 31;
            *(bf16x8*)&Ks[row][(c ^ (row & 31)) * 8] = kbuf[ii];
        }
        #pragma unroll
        for (int ii = 0; ii < 4; ii++) {              // V^T tile 256x32 (swizzled) from regs
            const int idx = t + ii * 256;
            const int row = idx >> 2, c = idx & 3;
            *(bf16x8*)&Vt[row][(c ^ (row & 3)) * 8] = vbuf[ii];
        }
        __syncthreads();
        if (c0 + 32 < cend) load_tiles(c0 + 32);      // issue next-tile loads

        floatx4 s0 = zero4, s1 = zero4;
        #pragma unroll
        for (int ks = 0; ks < 8; ks++) {
            const int ch = ks * 4 + quad;
            const bf16x8 b0 = *(bf16x8*)&Ks[lane16][(ch ^ lane16) * 8];
            const bf16x8 b1 = *(bf16x8*)&Ks[16 + lane16][(ch ^ (16 + lane16)) * 8];
            s0 = __builtin_amdgcn_mfma_f32_16x16x32_bf16(qf[ks], b0, s0, 0, 0, 0);
            s1 = __builtin_amdgcn_mfma_f32_16x16x32_bf16(qf[ks], b1, s1, 0, 0, 0);
        }
        float alpha[4];
        #pragma unroll
        for (int r = 0; r < 4; r++) {
            const float v0 = s0[r] * scale, v1 = s1[r] * scale;
            float mx = fmaxf(v0, v1);
            #pragma unroll
            for (int o = 8; o > 0; o >>= 1) mx = fmaxf(mx, __shfl_xor(mx, o));
            const float mnew = fmaxf(mrow[r], mx);
            const float p0 = __expf(v0 - mnew), p1 = __expf(v1 - mnew);
            float ps = p0 + p1;
            #pragma unroll
            for (int o = 8; o > 0; o >>= 1) ps += __shfl_xor(ps, o);
            alpha[r] = __expf(mrow[r] - mnew);
            lrow[r] = lrow[r] * alpha[r] + ps;
            mrow[r] = mnew;
            const int row = quad * 4 + r;
            Ps[w][row][lane16] = (__bf16)p0;
            Ps[w][row][16 + lane16] = (__bf16)p1;
        }
        const bool need = (alpha[0] < 1.f) | (alpha[1] < 1.f) | (alpha[2] < 1.f) | (alpha[3] < 1.f);
        if (__any(need)) {
            #pragma unroll
            for (int nt = 0; nt < 16; nt++)
                #pragma unroll
                for (int r = 0; r < 4; r++) O[nt][r] *= alpha[r];
        }
        const bf16x8 pf = *(bf16x8*)&Ps[w][lane16][quad * 8];
        #pragma unroll
        for (int nt = 0; nt < 16; nt++) {
            const int vrow = nt * 16 + lane16;
            const bf16x8 vf = *(bf16x8*)&Vt[vrow][(quad ^ (vrow & 3)) * 8];
            O[nt] = __builtin_amdgcn_mfma_f32_16x16x32_bf16(pf, vf, O[nt], 0, 0, 0);
        }
    }
    #pragma unroll
    for (int r = 0; r < 4; r++) {
        const int row = rw + quad * 4 + r;
        #pragma unroll
        for (int nt = 0; nt < 16; nt++)
            part[(size_t)row * HID + nt * 16 + lane16] = __float2bfloat16(O[nt][r]);
        if (lane16 == 0) ml[cs * N_BONDS + row] = make_float2(mrow[r], lrow[r]);
    }
}

// ---------------- fused: combine bf16 partials -> @Wa -> sigmoid-gate -> msg ----------------
__global__ __launch_bounds__(256)
void attcombine_kernel(P8 parts, const float2* __restrict__ ml, const hbf16* __restrict__ Wta,
                       const float* __restrict__ inputs, const float* __restrict__ dmpnn,
                       const float* __restrict__ ww, const float* __restrict__ wb,
                       float* __restrict__ msg)
{
    __shared__ __align__(16) __bf16 Av[32][264];
    __shared__ float wgtS[32][10];
    __shared__ float dotS[32][2];
    const int t = threadIdx.x, w = t >> 6, ln = t & 63;
    const int lane16 = ln & 15, quad = ln >> 4;
    const int rb = blockIdx.x * 32;
    const int mt = w & 1, nh = w >> 1;

    if (t < 32) {
        const int row = rb + t;
        float2 e[CS];
        float M = -1e30f;
        #pragma unroll
        for (int i = 0; i < CS; i++) { e[i] = ml[i * N_BONDS + row]; M = fmaxf(M, e[i].x); }
        float den = 0.f;
        #pragma unroll
        for (int i = 0; i < CS; i++) {
            const float g = __expf(e[i].x - M);
            wgtS[t][i] = g;
            den += g * e[i].y;
        }
        wgtS[t][8] = 1.f / den;
    }
    __syncthreads();
    for (int e = t; e < 32 * 64; e += 256) {
        const int row = e >> 6, c4 = (e & 63) * 4;
        const float inv = wgtS[row][8];
        float ax = 0.f, ay = 0.f, az = 0.f, aw = 0.f;
        #pragma unroll
        for (int i = 0; i < CS; i++) {
            const float g = wgtS[row][i];
            const bf16x4 pv = *(const bf16x4*)&parts.p[i][(size_t)(rb + row) * HID + c4];
            ax += g * (float)pv[0]; ay += g * (float)pv[1];
            az += g * (float)pv[2]; aw += g * (float)pv[3];
        }
        Av[row][c4 + 0] = (__bf16)(ax * inv);
        Av[row][c4 + 1] = (__bf16)(ay * inv);
        Av[row][c4 + 2] = (__bf16)(az * inv);
        Av[row][c4 + 3] = (__bf16)(aw * inv);
    }
    __syncthreads();

    const floatx4 zero4 = {0.f, 0.f, 0.f, 0.f};
    floatx4 acc[8];
    #pragma unroll
    for (int nt = 0; nt < 8; nt++) acc[nt] = zero4;
    #pragma unroll
    for (int ks = 0; ks < 8; ks++) {
        const bf16x8 af = *(const bf16x8*)&Av[mt * 16 + lane16][ks * 32 + quad * 8];
        #pragma unroll
        for (int nt = 0; nt < 8; nt++) {
            const bf16x8 bf = *(const bf16x8*)
                &Wta[(size_t)(nh * 128 + nt * 16 + lane16) * HID + ks * 32 + quad * 8];
            acc[nt] = __builtin_amdgcn_mfma_f32_16x16x32_bf16(af, bf, acc[nt], 0, 0, 0);
        }
    }
    float w2[8];
    #pragma unroll
    for (int nt = 0; nt < 8; nt++) w2[nt] = ww[HID + nh * 128 + nt * 16 + lane16];
    #pragma unroll
    for (int r = 0; r < 4; r++) {
        const int row = rb + mt * 16 + quad * 4 + r;
        float dot = 0.f;
        #pragma unroll
        for (int nt = 0; nt < 8; nt++) {
            const int col = nh * 128 + nt * 16 + lane16;
            dot += acc[nt][r] * w2[nt] + dmpnn[(size_t)row * HID + col] * ww[col];
        }
        #pragma unroll
        for (int o = 8; o > 0; o >>= 1) dot += __shfl_xor(dot, o);
        if (lane16 == 0) dotS[row - rb][nh] = dot;
    }
    __syncthreads();
    #pragma unroll
    for (int r = 0; r < 4; r++) {
        const int row = rb + mt * 16 + quad * 4 + r;
        const float alpha = 1.f / (1.f + __expf(-(dotS[row - rb][0] + dotS[row - rb][1] + wb[0])));
        #pragma unroll
        for (int nt = 0; nt < 8; nt++) {
            const int col = nh * 128 + nt * 16 + lane16;
            const float dv = dmpnn[(size_t)row * HID + col];
            const float v = inputs[(size_t)row * HID + col] + alpha * dv + (1.f - alpha) * acc[nt][r];
            msg[(size_t)row * HID + col] = fmaxf(v, 0.f);
        }
    }
}

// ---------------- small fused kernels ----------------
__global__ void gather_kernel(const float* __restrict__ msg, const int* __restrict__ a2b,
                              float* __restrict__ amsg)
{
    const int a = blockIdx.x, h = threadIdx.x;
    float s = 0.f;
    #pragma unroll
    for (int i = 0; i < 6; i++) {
        const int b = a2b[a * 6 + i];
        s += msg[(size_t)b * HID + h];
    }
    amsg[(size_t)a * HID + h] = s;
}

__global__ void gather_pre_kernel(const float* __restrict__ msg, const int* __restrict__ a2b,
                                  const int* __restrict__ b2a, const int* __restrict__ b2revb,
                                  float* __restrict__ pre)
{
    const int b = blockIdx.x, h = threadIdx.x;
    const int a = b2a[b];
    float s = -msg[(size_t)b2revb[b] * HID + h];
    #pragma unroll
    for (int i = 0; i < 6; i++)
        s += msg[(size_t)a2b[a * 6 + i] * HID + h];
    pre[(size_t)b * HID + h] = s;
}

__global__ void concat_kernel(const float* __restrict__ fe, const float* __restrict__ amsg,
                              float* __restrict__ ai)
{
    const int a = blockIdx.x, t = threadIdx.x;
    for (int f = t; f < FDIM; f += 256) ai[(size_t)a * AI_S + f] = fe[(size_t)a * FDIM + f];
    for (int h = t; h < HID; h += 256) ai[(size_t)a * AI_S + FDIM + h] = amsg[(size_t)a * HID + h];
    for (int z = t; z < AI_S - FDIM - HID; z += 256) ai[(size_t)a * AI_S + FDIM + HID + z] = 0.f;
}

// ---------------- launch ----------------
extern "C" void kernel_launch(void* const* d_in, const int* in_sizes, int n_in,
                              void* d_out, int out_size, void* d_ws, size_t ws_size,
                              hipStream_t stream)
{
    const int* a2b    = (const int*)d_in[19];
    const int* b2a    = (const int*)d_in[20];
    const int* b2revb = (const int*)d_in[21];

    float* ws = (float*)d_ws;
    size_t off = 0;
    auto alloc = [&](size_t n) { float* p = ws + off; off += (n + 63) & ~(size_t)63; return p; };
    int* flag = (int*)alloc(64);

    float* ln_g     = alloc(FDIM);
    float* ln_b     = alloc(FDIM);
    float* Walpha_w = alloc(2 * HID);
    float* Walpha_b = alloc(64);
    float* Wo_b     = alloc(HID);
    float* Wb_b     = alloc(HID);
    float* f_atoms_p = alloc((size_t)N_ATOMS * FA_S);
    float* f_bonds_p = alloc((size_t)N_BONDS * FB_S);
    auto balloc = [&](size_t n) { return (hbf16*)alloc((n + 1) / 2); };
    hbf16* Wt_qa = balloc((size_t)192 * FA_S);
    hbf16* Wt_ka = balloc((size_t)192 * FA_S);
    hbf16* Wt_va = balloc((size_t)192 * FA_S);
    hbf16* Wt_i  = balloc((size_t)HID * FB_S);
    hbf16* Wt_h  = balloc((size_t)HID * HID);
    hbf16* Wt_q  = balloc((size_t)HID * HID);
    hbf16* Wt_k  = balloc((size_t)HID * HID);
    hbf16* Wt_v  = balloc((size_t)HID * HID);
    hbf16* Wt_a  = balloc((size_t)HID * HID);
    hbf16* Wt_b  = balloc((size_t)HID * HID);
    hbf16* Wt_o  = balloc((size_t)HID * AI_S);

    float* f_e    = alloc((size_t)N_ATOMS * FDIM);
    float* inputs = alloc((size_t)N_BONDS * HID);
    float* msg    = alloc((size_t)N_BONDS * HID);
    float* buf1   = alloc((size_t)N_BONDS * HID);   // qa | pre | a_input
    float* buf2   = alloc((size_t)N_BONDS * HID);   // ka | dmpnn
    float* buf3   = alloc((size_t)N_BONDS * HID);   // vT | hmWa
    float* buf4   = alloc((size_t)N_BONDS * HID);   // atom_h
    float* amsg   = alloc((size_t)N_ATOMS * HID);
    float2* ml    = (float2*)alloc((size_t)CS * N_BONDS * 2);
    hbf16* Qb  = balloc((size_t)N_BONDS * HID);     // later: hm_hi
    hbf16* Kb  = balloc((size_t)N_BONDS * HID);     // later: hm_lo
    hbf16* Vtg = balloc((size_t)N_BONDS * HID);     // later: hmT
    hbf16* parts_mem = balloc((size_t)CS * N_BONDS * HID);   // bf16 partials (32MB)
    hbf16* vTa = (hbf16*)buf3;                       // atom V^T [192][4096]

    detect_kernel<<<1, 64, 0, stream>>>((const unsigned short*)d_in[1], flag);

    CvtTab ct;
    ct.src[0] = d_in[5];  ct.dst[0] = ln_g;     ct.n[0] = FDIM;
    ct.src[1] = d_in[6];  ct.dst[1] = ln_b;     ct.n[1] = FDIM;
    ct.src[2] = d_in[13]; ct.dst[2] = Walpha_w; ct.n[2] = 2 * HID;
    ct.src[3] = d_in[14]; ct.dst[3] = Walpha_b; ct.n[3] = 1;
    ct.src[4] = d_in[16]; ct.dst[4] = Wo_b;     ct.n[4] = HID;
    ct.src[5] = d_in[18]; ct.dst[5] = Wb_b;     ct.n[5] = HID;
    small_cvt_kernel<<<1, 256, 0, stream>>>(ct, flag);

    cvt_pad_kernel<<<(N_ATOMS * FA_S + 255) / 256, 256, 0, stream>>>(
        d_in[0], f_atoms_p, N_ATOMS, FDIM, FA_S, flag);
    cvt_pad_kernel<<<(N_BONDS * FB_S + 255) / 256, 256, 0, stream>>>(
        d_in[1], f_bonds_p, N_BONDS, BFDIM, FB_S, flag);

    WTab wt;
    const void* wsrc[11] = {d_in[2], d_in[3], d_in[4], d_in[7], d_in[8], d_in[9],
                            d_in[10], d_in[11], d_in[12], d_in[17], d_in[15]};
    hbf16* wdst[11] = {Wt_qa, Wt_ka, Wt_va, Wt_i, Wt_h, Wt_q, Wt_k, Wt_v, Wt_a, Wt_b, Wt_o};
    const int wK[11]  = {FDIM, FDIM, FDIM, BFDIM, HID, HID, HID, HID, HID, HID, FDIM + HID};
    const int wH[11]  = {FDIM, FDIM, FDIM, HID, HID, HID, HID, HID, HID, HID, HID};
    const int wKp[11] = {FA_S, FA_S, FA_S, FB_S, HID, HID, HID, HID, HID, HID, AI_S};
    const int wHp[11] = {192, 192, 192, HID, HID, HID, HID, HID, HID, HID, HID};
    for (int i = 0; i < 11; i++) {
        wt.src[i] = wsrc[i]; wt.dst[i] = wdst[i]; wt.K[i] = wK[i]; wt.Hout[i] = wH[i];
        wt.Kp[i] = wKp[i]; wt.total[i] = wHp[i] * wKp[i];
    }
    wt_all_kernel<<<dim3(416, 11), 256, 0, stream>>>(wt, flag);

    auto mg = [&](const float* A, int lda, const hbf16* Wt, const float* bias,
                  float* Cf, float* Cf2, int ldcf, hbf16* Cbh, hbf16* Cbl, int ldcb,
                  hbf16* CbT, int ldct, int rows, int Hout, int HoutStore, int relu) {
        dim3 grid((HoutStore + 63) / 64, rows / 64);
        mgemm_kernel<<<grid, 256, 0, stream>>>(A, lda, Wt, bias, Cf, Cf2, ldcf,
                                               Cbh, Cbl, ldcb, CbT, ldct,
                                               Hout, HoutStore, relu);
    };

    // --- atom self-attention stage ---
    mg(f_atoms_p, FA_S, Wt_qa, nullptr, buf1, nullptr, FA_S, nullptr, nullptr, 0,
       nullptr, 0, N_ATOMS, FDIM, FA_S, 0);                                     // qa
    mg(f_atoms_p, FA_S, Wt_ka, nullptr, buf2, nullptr, FA_S, nullptr, nullptr, 0,
       nullptr, 0, N_ATOMS, FDIM, FA_S, 0);                                     // ka
    mg(f_atoms_p, FA_S, Wt_va, nullptr, nullptr, nullptr, 0, nullptr, nullptr, 0,
       vTa, N_ATOMS, N_ATOMS, FDIM, 192, 0);                                    // vT
    atom_fused_kernel<<<NMOL, 256, 0, stream>>>(buf1, buf2, vTa, f_atoms_p, ln_g, ln_b, f_e);

    // --- bond init: inputs = f_bonds@Wi, msg = relu(inputs) ---
    mg(f_bonds_p, FB_S, Wt_i, nullptr, inputs, msg, HID, nullptr, nullptr, 0,
       nullptr, 0, N_BONDS, HID, HID, 0);

    P8 parts;
    for (int i = 0; i < CS; i++) parts.p[i] = parts_mem + (size_t)i * N_BONDS * HID;
    PROJ pj;
    pj.A[0] = buf1; pj.w[0] = Wt_h; pj.outp[0] = buf2; pj.mode[0] = 2;   // dmpnn (f32)
    pj.A[1] = msg;  pj.w[1] = Wt_q; pj.outp[1] = Qb;   pj.mode[1] = 0;   // Q bf16
    pj.A[2] = msg;  pj.w[2] = Wt_k; pj.outp[2] = Kb;   pj.mode[2] = 0;   // K bf16
    pj.A[3] = msg;  pj.w[3] = Wt_v; pj.outp[3] = Vtg;  pj.mode[3] = 1;   // V^T bf16

    // --- message passing ---
    for (int d = 0; d < 3; d++) {
        gather_pre_kernel<<<N_BONDS, 256, 0, stream>>>(msg, a2b, b2a, b2revb, buf1);
        proj_kernel<<<dim3(4, N_BONDS / 64, 4), 256, 0, stream>>>(pj);
        flash_kernel<<<dim3(CS, N_BONDS / 64), 256, 0, stream>>>(Qb, Kb, Vtg, parts, ml);
        attcombine_kernel<<<N_BONDS / 32, 256, 0, stream>>>(parts, ml, Wt_a, inputs,
                                                            buf2, Walpha_w, Walpha_b, msg);
    }

    // --- readout ---
    gather_kernel<<<N_ATOMS, 256, 0, stream>>>(msg, a2b, amsg);
    concat_kernel<<<N_ATOMS, 256, 0, stream>>>(f_e, amsg, buf1);                // a_input
    mg(buf1, AI_S, Wt_o, Wo_b, buf4, nullptr, HID, Qb, Kb, HID,
       Vtg, N_ATOMS, N_ATOMS, HID, HID, 1);                                     // atom_h

    // --- pooling ---
    mg(buf4, HID, Wt_a, nullptr, buf3, nullptr, HID, nullptr, nullptr, 0,
       nullptr, 0, N_ATOMS, HID, HID, 0);                                       // hmWa
    pool_fused_kernel<<<NMOL, 256, 0, stream>>>(buf3, buf4, Qb, Kb, Vtg, Wt_b,
                                                Wb_b, d_out, flag);
}